// Round 2
// baseline (2859.268 us; speedup 1.0000x reference)
//
#include <hip/hip_runtime.h>
#include <math.h>

// DSTA-Net block, fp32. N=64 C=128 CI=32 S=3 T=64 V=25.
// ws peak 90.5 MiB:
//   QKH [0,          9830400)  floats (39.3MB) - half-batch qk / quarter-batch MID
//   ATT [9830400,   10616832)  floats (3.1MB)
//   YB  [10616832,  23724032)  floats (52.4MB)
// d_out doubles as scratch for YA (spatial conv_out result) and ZA (temporal).

#define N_ 64
#define C_ 128
#define CI_ 32
#define S_ 3
#define T_ 64
#define V_ 25
#define O_IN 192
#define EPS_ 1e-5f
#define TV_ 1600  // T_*V_

// ---------------------------------------------------------------------------
// qk[n,o,t,v] = sum_c w[o,c]*(in[n,c,t,v]+pe[c,t,v]) + b[o], o in [0,192)
// grid (T/4, 32), block 256. LDS 51.2KB. Each thread: 4 og x 2 p.
__global__ __launch_bounds__(256) void k_conv_in(
    const float* __restrict__ in, const float* __restrict__ pe,
    const float* __restrict__ w, const float* __restrict__ b,
    float* __restrict__ qk) {
  const int t0 = blockIdx.x * 4, n = blockIdx.y;
  __shared__ float xs[C_][100];
  const float* inb = in + (size_t)n * C_ * TV_;
  for (int idx = threadIdx.x; idx < C_ * 100; idx += 256) {
    int c = idx / 100, p = idx % 100;
    int off = c * TV_ + t0 * V_ + p;
    xs[c][p] = inb[off] + pe[off];
  }
  __syncthreads();
  float* qkb = qk + (size_t)n * O_IN * TV_ + t0 * V_;
  for (int item = threadIdx.x; item < 48 * 50; item += 256) {
    int og = item / 50, pg = item % 50;
    float a[8];
#pragma unroll
    for (int k = 0; k < 4; ++k) { a[2 * k] = b[og + 48 * k]; a[2 * k + 1] = a[2 * k]; }
    const float* w0 = w + og * C_;
    const float* w1 = w + (og + 48) * C_;
    const float* w2 = w + (og + 96) * C_;
    const float* w3 = w + (og + 144) * C_;
#pragma unroll 4
    for (int c = 0; c < C_; ++c) {
      float y0 = xs[c][pg], y1 = xs[c][pg + 50];
      float wv0 = w0[c], wv1 = w1[c], wv2 = w2[c], wv3 = w3[c];
      a[0] += wv0 * y0; a[1] += wv0 * y1;
      a[2] += wv1 * y0; a[3] += wv1 * y1;
      a[4] += wv2 * y0; a[5] += wv2 * y1;
      a[6] += wv3 * y0; a[7] += wv3 * y1;
    }
#pragma unroll
    for (int k = 0; k < 4; ++k) {
      qkb[(size_t)(og + 48 * k) * TV_ + pg] = a[2 * k];
      qkb[(size_t)(og + 48 * k) * TV_ + pg + 50] = a[2 * k + 1];
    }
  }
}

// ---------------------------------------------------------------------------
// att_s[n,s,u,v] = tanh(sum_{c,t} q[c,t,u]*k[c,t,v] / 2048)*alpha[s] + att0[s,u,v]
// grid (S, 32), block 256. LDS 12.8KB.
__global__ __launch_bounds__(256) void k_gram_s(
    const float* __restrict__ qk, const float* __restrict__ alphas,
    const float* __restrict__ att0, float* __restrict__ att) {
  const int s = blockIdx.x, n = blockIdx.y;
  const float* qb = qk + (size_t)(n * 6 + s) * CI_ * TV_;
  const float* kb = qk + (size_t)(n * 6 + 3 + s) * CI_ * TV_;
  __shared__ float qs[64][V_];
  __shared__ float ks[64][V_];
  float acc0 = 0.f, acc1 = 0.f, acc2 = 0.f;
  for (int r0 = 0; r0 < CI_ * T_; r0 += 64) {
    for (int idx = threadIdx.x; idx < 64 * V_; idx += 256) {
      qs[idx / V_][idx % V_] = qb[(size_t)r0 * V_ + idx];
      ks[idx / V_][idx % V_] = kb[(size_t)r0 * V_ + idx];
    }
    __syncthreads();
    {
      int o0 = threadIdx.x;
      int o1 = threadIdx.x + 256;
      int o2 = threadIdx.x + 512;
      int u0 = o0 / 25, v0 = o0 % 25;
      int u1 = o1 / 25, v1 = o1 % 25;
      int u2 = (o2 < 625) ? o2 / 25 : 0, v2 = (o2 < 625) ? o2 % 25 : 0;
      float a0 = 0.f, a1 = 0.f, a2 = 0.f;
#pragma unroll 4
      for (int r = 0; r < 64; ++r) {
        a0 += qs[r][u0] * ks[r][v0];
        a1 += qs[r][u1] * ks[r][v1];
        a2 += qs[r][u2] * ks[r][v2];
      }
      acc0 += a0; acc1 += a1; acc2 += a2;
    }
    __syncthreads();
  }
  float al = alphas[s];
  float* ab = att + (size_t)(n * 3 + s) * 625;
  int o0 = threadIdx.x, o1 = threadIdx.x + 256, o2 = threadIdx.x + 512;
  ab[o0] = tanhf(acc0 * (1.0f / 2048.0f)) * al + att0[s * 625 + o0];
  ab[o1] = tanhf(acc1 * (1.0f / 2048.0f)) * al + att0[s * 625 + o1];
  if (o2 < 625)
    ab[o2] = tanhf(acc2 * (1.0f / 2048.0f)) * al + att0[s * 625 + o2];
}

// ---------------------------------------------------------------------------
// Fused spatial: ya[s,c,v] = sum_u x[c,u]*att[s,u,v];
// out[o,v] = lrelu(x[o,v] + bn(sum_sc w[o,sc]*ya[sc,v] + b[o]))
// grid (T, N), block 256. LDS 58.7KB.
__global__ __launch_bounds__(256) void k_apply_conv_s(
    const float* __restrict__ x, const float* __restrict__ att,
    const float* __restrict__ w, const float* __restrict__ b,
    const float* __restrict__ g, const float* __restrict__ be,
    const float* __restrict__ m, const float* __restrict__ vv,
    float* __restrict__ out) {
  const int t = blockIdx.x, n = blockIdx.y;
  __shared__ float xs[C_][V_];
  __shared__ float attl[S_ * V_ * V_];
  __shared__ float ya[S_ * C_][V_];
  const float* xb = x + (size_t)n * C_ * TV_ + t * V_;
  for (int idx = threadIdx.x; idx < C_ * V_; idx += 256) {
    int c = idx / V_, v = idx % V_;
    xs[c][v] = xb[(size_t)c * TV_ + v];
  }
  for (int idx = threadIdx.x; idx < S_ * V_ * V_; idx += 256)
    attl[idx] = att[(size_t)n * S_ * V_ * V_ + idx];
  __syncthreads();
  for (int idx = threadIdx.x; idx < S_ * C_ * V_; idx += 256) {
    int sc = idx / V_, v = idx % V_;
    int s = sc / C_, c = sc % C_;
    const float* ap = attl + s * V_ * V_ + v;
    float a = 0.f;
#pragma unroll
    for (int u = 0; u < V_; ++u) a += xs[c][u] * ap[u * V_];
    ya[sc][v] = a;
  }
  __syncthreads();
  float* ob = out + (size_t)n * C_ * TV_ + t * V_;
  for (int item = threadIdx.x; item < 32 * V_; item += 256) {
    int og = item / V_, v = item % V_;
    float a0 = 0.f, a1 = 0.f, a2 = 0.f, a3 = 0.f;
    const float* w0 = w + og * (S_ * C_);
    const float* w1 = w + (og + 32) * (S_ * C_);
    const float* w2 = w + (og + 64) * (S_ * C_);
    const float* w3 = w + (og + 96) * (S_ * C_);
#pragma unroll 4
    for (int sc = 0; sc < S_ * C_; ++sc) {
      float yv = ya[sc][v];
      a0 += w0[sc] * yv; a1 += w1[sc] * yv; a2 += w2[sc] * yv; a3 += w3[sc] * yv;
    }
    float accs[4] = {a0, a1, a2, a3};
#pragma unroll
    for (int k = 0; k < 4; ++k) {
      int o = og + 32 * k;
      float inv = g[o] * rsqrtf(vv[o] + EPS_);
      float bnv = (accs[k] + b[o] - m[o]) * inv + be[o];
      float val = xs[o][v] + bnv;
      ob[(size_t)o * TV_ + v] = val > 0.f ? val : 0.1f * val;
    }
  }
}

// ---------------------------------------------------------------------------
// FF conv: out[o,p] = lrelu(res[o,p] + bn(sum_c w[o,c]*yin[c,p] + b[o]))
// grid (T/4, N), block 256. LDS 51.2KB. Safe when out==yin (block-local tiles).
__global__ __launch_bounds__(256) void k_ff(
    const float* yin, const float* res,
    const float* __restrict__ w, const float* __restrict__ b,
    const float* __restrict__ g, const float* __restrict__ be,
    const float* __restrict__ m, const float* __restrict__ vv,
    float* out) {
  const int t0 = blockIdx.x * 4, n = blockIdx.y;
  __shared__ float ys[C_][100];
  const float* yb = yin + (size_t)n * C_ * TV_ + t0 * V_;
  for (int idx = threadIdx.x; idx < C_ * 100; idx += 256) {
    int c = idx / 100, p = idx % 100;
    ys[c][p] = yb[(size_t)c * TV_ + p];
  }
  __syncthreads();
  const float* rb = res + (size_t)n * C_ * TV_ + t0 * V_;
  float* ob = out + (size_t)n * C_ * TV_ + t0 * V_;
  for (int item = threadIdx.x; item < 32 * 50; item += 256) {
    int og = item / 50, pg = item % 50;
    float a[8] = {0.f, 0.f, 0.f, 0.f, 0.f, 0.f, 0.f, 0.f};
    const float* w0 = w + og * C_;
    const float* w1 = w + (og + 32) * C_;
    const float* w2 = w + (og + 64) * C_;
    const float* w3 = w + (og + 96) * C_;
#pragma unroll 4
    for (int c = 0; c < C_; ++c) {
      float y0 = ys[c][pg], y1 = ys[c][pg + 50];
      float wv0 = w0[c], wv1 = w1[c], wv2 = w2[c], wv3 = w3[c];
      a[0] += wv0 * y0; a[1] += wv0 * y1;
      a[2] += wv1 * y0; a[3] += wv1 * y1;
      a[4] += wv2 * y0; a[5] += wv2 * y1;
      a[6] += wv3 * y0; a[7] += wv3 * y1;
    }
#pragma unroll
    for (int k = 0; k < 4; ++k) {
      int o = og + 32 * k;
      float inv = g[o] * rsqrtf(vv[o] + EPS_);
      float bi = b[o], mo = m[o], beo = be[o];
#pragma unroll
      for (int pp = 0; pp < 2; ++pp) {
        int p = pg + 50 * pp;
        float bnv = (a[2 * k + pp] + bi - mo) * inv + beo;
        float val = rb[(size_t)o * TV_ + p] + bnv;
        ob[(size_t)o * TV_ + p] = val > 0.f ? val : 0.1f * val;
      }
    }
  }
}

// ---------------------------------------------------------------------------
// att_t[n,s,t,q] = tanh(sum_{c,v} q[c,t,v]*k[c,q,v] / 800)*alpha[s] + att0[s,t,q]
// grid (S, 32), block 256 (each thread one 4x4 (t,q) tile). LDS 51.2KB.
__global__ __launch_bounds__(256) void k_gram_t(
    const float* __restrict__ qk, const float* __restrict__ alphat,
    const float* __restrict__ att0, float* __restrict__ att) {
  const int s = blockIdx.x, n = blockIdx.y;
  const float* qb = qk + (size_t)(n * 6 + s) * CI_ * TV_;
  const float* kb = qk + (size_t)(n * 6 + 3 + s) * CI_ * TV_;
  __shared__ float qs[4 * TV_];
  __shared__ float ks[4 * TV_];
  const int tg = threadIdx.x >> 4, qg = threadIdx.x & 15;
  const int t0 = tg * 4, q0 = qg * 4;
  float acc[4][4] = {};
  for (int c0 = 0; c0 < CI_; c0 += 4) {
    for (int idx = threadIdx.x; idx < 4 * TV_; idx += 256) {
      qs[idx] = qb[(size_t)c0 * TV_ + idx];
      ks[idx] = kb[(size_t)c0 * TV_ + idx];
    }
    __syncthreads();
#pragma unroll
    for (int cc = 0; cc < 4; ++cc) {
      const float* qr = qs + cc * TV_;
      const float* kr = ks + cc * TV_;
#pragma unroll 5
      for (int v = 0; v < 25; ++v) {
        float qv0 = qr[(t0 + 0) * 25 + v];
        float qv1 = qr[(t0 + 1) * 25 + v];
        float qv2 = qr[(t0 + 2) * 25 + v];
        float qv3 = qr[(t0 + 3) * 25 + v];
        float kv0 = kr[(q0 + 0) * 25 + v];
        float kv1 = kr[(q0 + 1) * 25 + v];
        float kv2 = kr[(q0 + 2) * 25 + v];
        float kv3 = kr[(q0 + 3) * 25 + v];
        acc[0][0] += qv0 * kv0; acc[0][1] += qv0 * kv1; acc[0][2] += qv0 * kv2; acc[0][3] += qv0 * kv3;
        acc[1][0] += qv1 * kv0; acc[1][1] += qv1 * kv1; acc[1][2] += qv1 * kv2; acc[1][3] += qv1 * kv3;
        acc[2][0] += qv2 * kv0; acc[2][1] += qv2 * kv1; acc[2][2] += qv2 * kv2; acc[2][3] += qv2 * kv3;
        acc[3][0] += qv3 * kv0; acc[3][1] += qv3 * kv1; acc[3][2] += qv3 * kv2; acc[3][3] += qv3 * kv3;
      }
    }
    __syncthreads();
  }
  float al = alphat[s];
  float* ab = att + (size_t)(n * 3 + s) * 4096;
#pragma unroll
  for (int j = 0; j < 4; ++j)
#pragma unroll
    for (int i = 0; i < 4; ++i) {
      int t = t0 + j, q = q0 + i;
      ab[t * 64 + q] = tanhf(acc[j][i] * (1.0f / 800.0f)) * al + att0[(size_t)s * 4096 + t * 64 + q];
    }
}

// ---------------------------------------------------------------------------
// Temporal apply (quarter batch): mid[n2,s,c,q,v] = sum_t y[n2,c,t,v]*att[n2,s,t,q]
// grid (C/2, 16), block 256. LDS 12.8KB; att read via L1 (float4, lane-shared).
__global__ __launch_bounds__(256) void k_apply_t(
    const float* __restrict__ y, const float* __restrict__ att,
    float* __restrict__ mid) {
  const int cg = blockIdx.x, n2 = blockIdx.y;
  __shared__ float ys[2 * TV_];
  const float* ybase = y + ((size_t)n2 * C_ + cg * 2) * TV_;
  for (int idx = threadIdx.x; idx < 2 * TV_; idx += 256) ys[idx] = ybase[idx];
  __syncthreads();
  const float* ab = att + (size_t)n2 * 3 * 4096;
  for (int item = threadIdx.x; item < 1200; item += 256) {
    int s = item / 400, rem = item % 400, qg = rem / 25, v = rem % 25;
    int q0 = qg * 4;
    const float* ap = ab + s * 4096 + q0;
    float acc[2][4] = {};
#pragma unroll 4
    for (int t = 0; t < 64; ++t) {
      float4 av = *(const float4*)(ap + t * 64);
      float y0 = ys[t * 25 + v];
      float y1 = ys[TV_ + t * 25 + v];
      acc[0][0] += y0 * av.x; acc[0][1] += y0 * av.y; acc[0][2] += y0 * av.z; acc[0][3] += y0 * av.w;
      acc[1][0] += y1 * av.x; acc[1][1] += y1 * av.y; acc[1][2] += y1 * av.z; acc[1][3] += y1 * av.w;
    }
    float* mb = mid + (((size_t)n2 * 3 + s) * C_ + cg * 2) * TV_ + v;
#pragma unroll
    for (int ci = 0; ci < 2; ++ci)
#pragma unroll
      for (int qj = 0; qj < 4; ++qj)
        mb[(size_t)ci * TV_ + (q0 + qj) * 25] = acc[ci][qj];
  }
}

// ---------------------------------------------------------------------------
// Temporal conv_out (quarter batch): out[o,p] = lrelu(res + bn(sum_sc w[o,sc]*mid[sc,p]+b))
// grid (T/4, 16), block 256. LDS 51.2KB, persistent acc over 3 sc-chunks.
__global__ __launch_bounds__(256) void k_conv384(
    const float* __restrict__ mid, const float* __restrict__ res,
    const float* __restrict__ w, const float* __restrict__ b,
    const float* __restrict__ g, const float* __restrict__ be,
    const float* __restrict__ m, const float* __restrict__ vv,
    float* __restrict__ out) {
  const int q0 = blockIdx.x * 4, n2 = blockIdx.y;
  __shared__ float ms[C_][100];
  float acc[7][8];
#pragma unroll
  for (int j = 0; j < 7; ++j)
#pragma unroll
    for (int k = 0; k < 8; ++k) acc[j][k] = 0.f;

  for (int chunk = 0; chunk < 3; ++chunk) {
    const float* mb = mid + ((size_t)n2 * 384 + chunk * 128) * TV_ + q0 * V_;
    for (int idx = threadIdx.x; idx < C_ * 100; idx += 256) {
      int cc = idx / 100, p = idx % 100;
      ms[cc][p] = mb[(size_t)cc * TV_ + p];
    }
    __syncthreads();
#pragma unroll
    for (int j = 0; j < 7; ++j) {
      int item = threadIdx.x + j * 256;
      if (item < 1600) {
        int og = item / 50, pg = item % 50;
        const float* w0 = w + og * 384 + chunk * 128;
        const float* w1 = w + (og + 32) * 384 + chunk * 128;
        const float* w2 = w + (og + 64) * 384 + chunk * 128;
        const float* w3 = w + (og + 96) * 384 + chunk * 128;
        float a0 = acc[j][0], a1 = acc[j][1], a2 = acc[j][2], a3 = acc[j][3];
        float a4 = acc[j][4], a5 = acc[j][5], a6 = acc[j][6], a7 = acc[j][7];
#pragma unroll 4
        for (int cc = 0; cc < 128; ++cc) {
          float y0 = ms[cc][pg], y1 = ms[cc][pg + 50];
          float wv0 = w0[cc], wv1 = w1[cc], wv2 = w2[cc], wv3 = w3[cc];
          a0 += wv0 * y0; a1 += wv0 * y1;
          a2 += wv1 * y0; a3 += wv1 * y1;
          a4 += wv2 * y0; a5 += wv2 * y1;
          a6 += wv3 * y0; a7 += wv3 * y1;
        }
        acc[j][0] = a0; acc[j][1] = a1; acc[j][2] = a2; acc[j][3] = a3;
        acc[j][4] = a4; acc[j][5] = a5; acc[j][6] = a6; acc[j][7] = a7;
      }
    }
    __syncthreads();
  }
  const float* rb = res + (size_t)n2 * C_ * TV_ + q0 * V_;
  float* ob = out + (size_t)n2 * C_ * TV_ + q0 * V_;
#pragma unroll
  for (int j = 0; j < 7; ++j) {
    int item = threadIdx.x + j * 256;
    if (item < 1600) {
      int og = item / 50, pg = item % 50;
#pragma unroll
      for (int k = 0; k < 4; ++k) {
        int o = og + 32 * k;
        float inv = g[o] * rsqrtf(vv[o] + EPS_);
        float bi = b[o], mo = m[o], beo = be[o];
#pragma unroll
        for (int pp = 0; pp < 2; ++pp) {
          int p = pg + 50 * pp;
          float bnv = (acc[j][2 * k + pp] + bi - mo) * inv + beo;
          float val = rb[(size_t)o * TV_ + p] + bnv;
          ob[(size_t)o * TV_ + p] = val > 0.f ? val : 0.1f * val;
        }
      }
    }
  }
}

// ---------------------------------------------------------------------------
extern "C" void kernel_launch(void* const* d_in, const int* in_sizes, int n_in,
                              void* d_out, int out_size, void* d_ws, size_t ws_size,
                              hipStream_t stream) {
  const float* x       = (const float*)d_in[0];
  const float* pe_s    = (const float*)d_in[1];
  const float* pe_t    = (const float*)d_in[2];
  const float* w_in_s  = (const float*)d_in[3];
  const float* b_in_s  = (const float*)d_in[4];
  const float* alphas  = (const float*)d_in[5];
  const float* att0s   = (const float*)d_in[6];
  const float* w_out_s = (const float*)d_in[7];
  const float* b_out_s = (const float*)d_in[8];
  const float* w_ff_s  = (const float*)d_in[9];
  const float* b_ff_s  = (const float*)d_in[10];
  const float* w_in_t  = (const float*)d_in[11];
  const float* b_in_t  = (const float*)d_in[12];
  const float* alphat  = (const float*)d_in[13];
  const float* att0t   = (const float*)d_in[14];
  const float* w_out_t = (const float*)d_in[15];
  const float* b_out_t = (const float*)d_in[16];
  const float* w_ff_t  = (const float*)d_in[17];
  const float* b_ff_t  = (const float*)d_in[18];
  const float* g_out_s  = (const float*)d_in[19];
  const float* be_out_s = (const float*)d_in[20];
  const float* m_out_s  = (const float*)d_in[21];
  const float* v_out_s  = (const float*)d_in[22];
  const float* g_ff_s   = (const float*)d_in[23];
  const float* be_ff_s  = (const float*)d_in[24];
  const float* m_ff_s   = (const float*)d_in[25];
  const float* v_ff_s   = (const float*)d_in[26];
  const float* g_out_t  = (const float*)d_in[27];
  const float* be_out_t = (const float*)d_in[28];
  const float* m_out_t  = (const float*)d_in[29];
  const float* v_out_t  = (const float*)d_in[30];
  const float* g_ff_t   = (const float*)d_in[31];
  const float* be_ff_t  = (const float*)d_in[32];
  const float* m_ff_t   = (const float*)d_in[33];
  const float* v_ff_t   = (const float*)d_in[34];
  (void)in_sizes; (void)n_in; (void)out_size; (void)ws_size;

  float* ws  = (float*)d_ws;
  float* QKH = ws;                 // 9,830,400 floats (half-batch qk / quarter MID)
  float* ATT = ws + 9830400;       //   786,432 floats
  float* YB  = ws + 10616832;      // 13,107,200 floats
  float* OUT = (float*)d_out;

  dim3 blk(256);
  const size_t NSTRIDE = (size_t)C_ * TV_;  // 204800 floats per batch item

  // ---- spatial block ----
  for (int h = 0; h < 2; ++h) {  // half-batch qk to bound ws
    const float* xh = x + (size_t)h * 32 * NSTRIDE;
    k_conv_in<<<dim3(16, 32), blk, 0, stream>>>(xh, pe_s, w_in_s, b_in_s, QKH);
    k_gram_s<<<dim3(3, 32), blk, 0, stream>>>(QKH, alphas, att0s,
        ATT + (size_t)h * 32 * 3 * 625);
  }
  k_apply_conv_s<<<dim3(64, 64), blk, 0, stream>>>(x, ATT, w_out_s, b_out_s,
      g_out_s, be_out_s, m_out_s, v_out_s, OUT);                       // OUT = YA
  k_ff<<<dim3(16, 64), blk, 0, stream>>>(OUT, x, w_ff_s, b_ff_s,
      g_ff_s, be_ff_s, m_ff_s, v_ff_s, YB);                            // YB

  // ---- temporal block ----
  for (int h = 0; h < 2; ++h) {
    const float* yh = YB + (size_t)h * 32 * NSTRIDE;
    k_conv_in<<<dim3(16, 32), blk, 0, stream>>>(yh, pe_t, w_in_t, b_in_t, QKH);
    k_gram_t<<<dim3(3, 32), blk, 0, stream>>>(QKH, alphat, att0t,
        ATT + (size_t)h * 32 * 3 * 4096);
  }
  for (int h = 0; h < 4; ++h) {  // quarter-batch MID reusing QKH
    const float* ybh  = YB  + (size_t)h * 16 * NSTRIDE;
    const float* atth = ATT + (size_t)h * 16 * 3 * 4096;
    float* outh = OUT + (size_t)h * 16 * NSTRIDE;
    k_apply_t<<<dim3(64, 16), blk, 0, stream>>>(ybh, atth, QKH);       // QKH = MID qtr
    k_conv384<<<dim3(16, 16), blk, 0, stream>>>(QKH, ybh, w_out_t, b_out_t,
        g_out_t, be_out_t, m_out_t, v_out_t, outh);                    // OUT = ZA
  }
  k_ff<<<dim3(16, 64), blk, 0, stream>>>(OUT, YB, w_ff_t, b_ff_t,
      g_ff_t, be_ff_t, m_ff_t, v_ff_t, OUT);                           // final, in-place
}

// Round 4
// 1086.727 us; speedup vs baseline: 2.6311x; 2.6311x over previous
//
#include <hip/hip_runtime.h>
#include <math.h>

// DSTA-Net block. N=64 C=128 CI=32 S=3 T=64 V=25.
// GEMMs on bf16 MFMA with hi/lo split (fp32-accurate, 3 mfma per term),
// attention gram/apply kernels on fp32 VALU.
//
// ws layouts (selected at runtime on ws_size):
//  FULL  (needs 134,938,624 B): QK 19660800 fl | ATT 786432 fl | YB 13107200 fl | WF 720896 B
//  CHUNK (needs  75,956,224 B): SCR 4915200 fl | ATT 786432 fl | YB 13107200 fl | WF 720896 B
//   (SCR = quarter-batch qk (16n*192*1600) == eighth-batch mid (8n*384*1600))
// d_out doubles as scratch for YA/ZA stage outputs.

#define EPS_ 1e-5f

typedef short bf16x8 __attribute__((ext_vector_type(8)));
typedef float f32x4 __attribute__((ext_vector_type(4)));

__device__ __forceinline__ unsigned short f2bf(float f) {
  unsigned u = __float_as_uint(f);
  unsigned r = u + 0x7fffu + ((u >> 16) & 1u);
  return (unsigned short)(r >> 16);
}
__device__ __forceinline__ float bf2f(unsigned short h) {
  return __uint_as_float((unsigned)h << 16);
}

// ---------------------------------------------------------------------------
// Weight splitter: W[O][K] fp32 -> fragment-ordered bf16 hi/lo.
// Frag f = ot*(K/32)+ks: hi at f*1024 + lane*8, lo at +512 (shorts).
// Element j of lane l: W[ot*16 + (l&15)][ks*32 + (l>>4)*8 + j].
struct SplitArgs {
  const float* src[6];
  unsigned short* dst[6];
  int K[6];
  int nfrag[6];
};
__global__ __launch_bounds__(64) void k_split_w(SplitArgs a) {
  const int mat = blockIdx.y;
  const int f = blockIdx.x;
  if (f >= a.nfrag[mat]) return;
  const int K = a.K[mat];
  const int ksteps = K >> 5;
  const int ot = f / ksteps, ks = f % ksteps;
  const int l = threadIdx.x;
  const float* sp = a.src[mat] + (size_t)(ot * 16 + (l & 15)) * K + ks * 32 + (l >> 4) * 8;
  float4 f0 = *(const float4*)sp;
  float4 f1 = *(const float4*)(sp + 4);
  float vals[8] = {f0.x, f0.y, f0.z, f0.w, f1.x, f1.y, f1.z, f1.w};
  unsigned short hi[8], lo[8];
#pragma unroll
  for (int j = 0; j < 8; ++j) {
    hi[j] = f2bf(vals[j]);
    lo[j] = f2bf(vals[j] - bf2f(hi[j]));
  }
  unsigned short* d = a.dst[mat] + (size_t)f * 1024 + l * 8;
  uint4 ph, pl;
  ph.x = hi[0] | ((unsigned)hi[1] << 16); ph.y = hi[2] | ((unsigned)hi[3] << 16);
  ph.z = hi[4] | ((unsigned)hi[5] << 16); ph.w = hi[6] | ((unsigned)hi[7] << 16);
  pl.x = lo[0] | ((unsigned)lo[1] << 16); pl.y = lo[2] | ((unsigned)lo[3] << 16);
  pl.z = lo[4] | ((unsigned)lo[5] << 16); pl.w = lo[6] | ((unsigned)lo[7] << 16);
  *(uint4*)d = ph;
  *(uint4*)(d + 512) = pl;
}

// ---------------------------------------------------------------------------
// MFMA conv: out[o,p] = epi( sum_k W[o,k] * Yin[k,p] ), p-tile of 64 per block.
// D[p][o] = A(Y^T) x B(W^T). A staged in LDS [p][k] (pad 136 shorts), hi/lo.
// EPI 0: +bias (qk output). EPI 1: bn(+bias)+residual+leakyrelu.
// grid (25, nN), block 256 (4 waves; wave w owns p-subtile w).
template <int KTOT, int OTOT, int EPI>
__global__ __launch_bounds__(256) void k_mfma_conv(
    const float* __restrict__ Yin, const float* __restrict__ pe,
    const unsigned short* __restrict__ WF, const float* __restrict__ bias,
    const float* __restrict__ g, const float* __restrict__ be,
    const float* __restrict__ bm, const float* __restrict__ bv,
    const float* __restrict__ res, float* __restrict__ out) {
  constexpr int KSTEPS = KTOT / 32;
  constexpr int NCHUNK = KTOT / 128;
  constexpr int OTILES = OTOT / 16;
  const size_t yin_ns = (size_t)KTOT * 1600;
  const size_t out_ns = (size_t)OTOT * 1600;

  __shared__ unsigned short Yhi[64][136];
  __shared__ unsigned short Ylo[64][136];
  __shared__ float ep0[OTOT], ep1[OTOT];

  const int tid = threadIdx.x;
  const int lane = tid & 63, wv = tid >> 6;
  const int n = blockIdx.y, p0 = blockIdx.x * 64;

  for (int i = tid; i < OTOT; i += 256) {
    if (EPI == 1) {
      float inv = g[i] * rsqrtf(bv[i] + EPS_);
      ep0[i] = inv;
      ep1[i] = be[i] + (bias[i] - bm[i]) * inv;
    } else {
      ep0[i] = bias[i];
    }
  }

  f32x4 acc[OTILES];
#pragma unroll
  for (int ot = 0; ot < OTILES; ++ot) acc[ot] = 0;

  const int pl = tid & 63, q = tid >> 6;
  for (int kc = 0; kc < NCHUNK; ++kc) {
    // stage Y^T tile: 128 k x 64 p, transposed into [p][k], hi/lo split
    const float* src = Yin + (size_t)n * yin_ns + (size_t)(kc * 128 + q * 32) * 1600 + p0 + pl;
    const float* pes = pe ? pe + (size_t)(kc * 128 + q * 32) * 1600 + p0 + pl : (const float*)0;
#pragma unroll
    for (int r = 0; r < 8; ++r) {
      float v4[4];
#pragma unroll
      for (int i = 0; i < 4; ++i) {
        v4[i] = src[(size_t)(r * 4 + i) * 1600];
        if (pe) v4[i] += pes[(size_t)(r * 4 + i) * 1600];
      }
      unsigned short h[4], lw[4];
#pragma unroll
      for (int i = 0; i < 4; ++i) {
        h[i] = f2bf(v4[i]);
        lw[i] = f2bf(v4[i] - bf2f(h[i]));
      }
      uint2 ph, plo;
      ph.x = h[0] | ((unsigned)h[1] << 16);  ph.y = h[2] | ((unsigned)h[3] << 16);
      plo.x = lw[0] | ((unsigned)lw[1] << 16); plo.y = lw[2] | ((unsigned)lw[3] << 16);
      *(uint2*)&Yhi[pl][q * 32 + r * 4] = ph;
      *(uint2*)&Ylo[pl][q * 32 + r * 4] = plo;
    }
    __syncthreads();

    const int rowA = wv * 16 + (lane & 15);
    const int kg = (lane >> 4) * 8;
#pragma unroll
    for (int ks = 0; ks < 4; ++ks) {
      bf16x8 ahi = *(const bf16x8*)&Yhi[rowA][ks * 32 + kg];
      bf16x8 alo = *(const bf16x8*)&Ylo[rowA][ks * 32 + kg];
#pragma unroll
      for (int ot = 0; ot < OTILES; ++ot) {
        const unsigned short* wp =
            WF + (size_t)(ot * KSTEPS + kc * 4 + ks) * 1024 + (lane << 3);
        bf16x8 whi = *(const bf16x8*)wp;
        bf16x8 wlo = *(const bf16x8*)(wp + 512);
        acc[ot] = __builtin_amdgcn_mfma_f32_16x16x32_bf16(ahi, whi, acc[ot], 0, 0, 0);
        acc[ot] = __builtin_amdgcn_mfma_f32_16x16x32_bf16(alo, whi, acc[ot], 0, 0, 0);
        acc[ot] = __builtin_amdgcn_mfma_f32_16x16x32_bf16(ahi, wlo, acc[ot], 0, 0, 0);
      }
    }
    __syncthreads();
  }

  // epilogue: lane&15 = o within tile; rows p = p0 + wv*16 + (lane>>4)*4 + j
  const int o_l = lane & 15;
  const int prow = p0 + wv * 16 + ((lane >> 4) << 2);
#pragma unroll
  for (int ot = 0; ot < OTILES; ++ot) {
    const int o = ot * 16 + o_l;
    f32x4 v = acc[ot];
    if (EPI == 1) {
      const float inv = ep0[o], beta = ep1[o];
      const f32x4 rv = *(const f32x4*)(res + (size_t)n * out_ns + (size_t)o * 1600 + prow);
#pragma unroll
      for (int j = 0; j < 4; ++j) {
        float val = v[j] * inv + beta + rv[j];
        v[j] = val > 0.f ? val : 0.1f * val;
      }
    } else {
      const float bo = ep0[o];
#pragma unroll
      for (int j = 0; j < 4; ++j) v[j] += bo;
    }
    *(f32x4*)(out + (size_t)n * out_ns + (size_t)o * 1600 + prow) = v;
  }
}

// ---------------------------------------------------------------------------
// att_s[n,s,u,v] = tanh(sum_{c,t} q[c,t,u]*k[c,t,v] / 2048)*alpha[s] + att0[s,u,v]
// grid (3, nN), block 256. LDS 25.6KB.
__global__ __launch_bounds__(256) void k_gram_s(
    const float* __restrict__ qk, const float* __restrict__ alphas,
    const float* __restrict__ att0, float* __restrict__ att) {
  const int s = blockIdx.x, n = blockIdx.y;
  const float* qb = qk + (size_t)(n * 6 + s) * 51200;
  const float* kb = qk + (size_t)(n * 6 + 3 + s) * 51200;
  __shared__ float qs[128][25];
  __shared__ float ksm[128][25];
  float a0 = 0.f, a1 = 0.f, a2 = 0.f;
  const int o0 = threadIdx.x, o1 = o0 + 256, o2 = o0 + 512;
  const int u0 = o0 / 25, v0 = o0 % 25;
  const int u1 = o1 / 25, v1 = o1 % 25;
  const int u2 = (o2 < 625) ? o2 / 25 : 0, v2 = (o2 < 625) ? o2 % 25 : 0;
  for (int r0 = 0; r0 < 2048; r0 += 128) {
    for (int idx = threadIdx.x; idx < 3200; idx += 256) {
      qs[idx / 25][idx % 25] = qb[(size_t)r0 * 25 + idx];
      ksm[idx / 25][idx % 25] = kb[(size_t)r0 * 25 + idx];
    }
    __syncthreads();
#pragma unroll 4
    for (int r = 0; r < 128; ++r) {
      a0 += qs[r][u0] * ksm[r][v0];
      a1 += qs[r][u1] * ksm[r][v1];
      a2 += qs[r][u2] * ksm[r][v2];
    }
    __syncthreads();
  }
  const float al = alphas[s];
  float* ab = att + (size_t)(n * 3 + s) * 625;
  ab[o0] = tanhf(a0 * (1.0f / 2048.0f)) * al + att0[s * 625 + o0];
  ab[o1] = tanhf(a1 * (1.0f / 2048.0f)) * al + att0[s * 625 + o1];
  if (o2 < 625)
    ab[o2] = tanhf(a2 * (1.0f / 2048.0f)) * al + att0[s * 625 + o2];
}

// ---------------------------------------------------------------------------
// att_t[n,s,t,q] = tanh(sum_{c,v} q[c,t,v]*k[c,q,v] / 800)*alpha[s] + att0[s,t,q]
// grid (3, nN), block 256 (thread = 4x4 (t,q) tile). LDS 51.2KB.
__global__ __launch_bounds__(256) void k_gram_t(
    const float* __restrict__ qk, const float* __restrict__ alphat,
    const float* __restrict__ att0, float* __restrict__ att) {
  const int s = blockIdx.x, n = blockIdx.y;
  const float* qb = qk + (size_t)(n * 6 + s) * 51200;
  const float* kb = qk + (size_t)(n * 6 + 3 + s) * 51200;
  __shared__ float qs[6400];
  __shared__ float ksm[6400];
  const int tg = threadIdx.x >> 4, qg = threadIdx.x & 15;
  const int t0 = tg * 4, q0 = qg * 4;
  float acc[4][4] = {};
  for (int c0 = 0; c0 < 32; c0 += 4) {
    for (int idx = threadIdx.x; idx < 6400; idx += 256) {
      qs[idx] = qb[(size_t)c0 * 1600 + idx];
      ksm[idx] = kb[(size_t)c0 * 1600 + idx];
    }
    __syncthreads();
#pragma unroll
    for (int cc = 0; cc < 4; ++cc) {
      const float* qr = qs + cc * 1600;
      const float* kr = ksm + cc * 1600;
#pragma unroll 5
      for (int v = 0; v < 25; ++v) {
        float qv0 = qr[(t0 + 0) * 25 + v], qv1 = qr[(t0 + 1) * 25 + v];
        float qv2 = qr[(t0 + 2) * 25 + v], qv3 = qr[(t0 + 3) * 25 + v];
        float kv0 = kr[(q0 + 0) * 25 + v], kv1 = kr[(q0 + 1) * 25 + v];
        float kv2 = kr[(q0 + 2) * 25 + v], kv3 = kr[(q0 + 3) * 25 + v];
        acc[0][0] += qv0 * kv0; acc[0][1] += qv0 * kv1; acc[0][2] += qv0 * kv2; acc[0][3] += qv0 * kv3;
        acc[1][0] += qv1 * kv0; acc[1][1] += qv1 * kv1; acc[1][2] += qv1 * kv2; acc[1][3] += qv1 * kv3;
        acc[2][0] += qv2 * kv0; acc[2][1] += qv2 * kv1; acc[2][2] += qv2 * kv2; acc[2][3] += qv2 * kv3;
        acc[3][0] += qv3 * kv0; acc[3][1] += qv3 * kv1; acc[3][2] += qv3 * kv2; acc[3][3] += qv3 * kv3;
      }
    }
    __syncthreads();
  }
  const float al = alphat[s];
  float* ab = att + (size_t)(n * 3 + s) * 4096;
#pragma unroll
  for (int j = 0; j < 4; ++j)
#pragma unroll
    for (int i = 0; i < 4; ++i) {
      int t = t0 + j, qq = q0 + i;
      ab[t * 64 + qq] =
          tanhf(acc[j][i] * (1.0f / 800.0f)) * al + att0[(size_t)s * 4096 + t * 64 + qq];
    }
}

// ---------------------------------------------------------------------------
// Spatial apply: ya[n,s*128+c, t*25+v] = sum_u x[n,c,t*25+u] * att[n,s,u,v]
// grid (64, nN), block 256. LDS 20.3KB.
__global__ __launch_bounds__(256) void k_apply_s(
    const float* __restrict__ x, const float* __restrict__ att,
    float* __restrict__ ya) {
  const int t = blockIdx.x, n = blockIdx.y;
  __shared__ float xs[128][25];
  __shared__ float al[1875];
  const float* xb = x + (size_t)n * 204800 + t * 25;
  for (int idx = threadIdx.x; idx < 3200; idx += 256)
    xs[idx / 25][idx % 25] = xb[(size_t)(idx / 25) * 1600 + idx % 25];
  for (int idx = threadIdx.x; idx < 1875; idx += 256)
    al[idx] = att[(size_t)n * 1875 + idx];
  __syncthreads();
  float* yb = ya + (size_t)n * 614400 + t * 25;
  for (int idx = threadIdx.x; idx < 9600; idx += 256) {
    const int s = idx / 3200, rem = idx - s * 3200;
    const int c = rem / 25, v = rem % 25;
    const float* ap = al + s * 625 + v;
    float a = 0.f;
#pragma unroll
    for (int u = 0; u < 25; ++u) a += xs[c][u] * ap[u * 25];
    yb[(size_t)(s * 128 + c) * 1600 + v] = a;
  }
}

// ---------------------------------------------------------------------------
// Temporal apply: mid[n, s*128+c, q*25+v] = sum_t y[n,c,t*25+v] * att[n,s,t*64+q]
// grid (64, nN), block 256. LDS 12.8KB.
__global__ __launch_bounds__(256) void k_apply_t(
    const float* __restrict__ y, const float* __restrict__ att,
    float* __restrict__ mid) {
  const int cg = blockIdx.x, n2 = blockIdx.y;
  __shared__ float ys[3200];
  const float* ybase = y + ((size_t)n2 * 128 + cg * 2) * 1600;
  for (int idx = threadIdx.x; idx < 3200; idx += 256) ys[idx] = ybase[idx];
  __syncthreads();
  const float* ab = att + (size_t)n2 * 3 * 4096;
  for (int item = threadIdx.x; item < 1200; item += 256) {
    const int s = item / 400, rem = item % 400, qg = rem / 25, v = rem % 25;
    const int q0 = qg * 4;
    const float* ap = ab + s * 4096 + q0;
    float acc[2][4] = {};
#pragma unroll 4
    for (int t = 0; t < 64; ++t) {
      float4 av = *(const float4*)(ap + t * 64);
      float y0 = ys[t * 25 + v];
      float y1 = ys[1600 + t * 25 + v];
      acc[0][0] += y0 * av.x; acc[0][1] += y0 * av.y; acc[0][2] += y0 * av.z; acc[0][3] += y0 * av.w;
      acc[1][0] += y1 * av.x; acc[1][1] += y1 * av.y; acc[1][2] += y1 * av.z; acc[1][3] += y1 * av.w;
    }
    float* mb = mid + (((size_t)n2 * 3 + s) * 128 + cg * 2) * 1600 + v;
#pragma unroll
    for (int ci = 0; ci < 2; ++ci)
#pragma unroll
      for (int qj = 0; qj < 4; ++qj)
        mb[(size_t)ci * 1600 + (q0 + qj) * 25] = acc[ci][qj];
  }
}

// ---------------------------------------------------------------------------
extern "C" void kernel_launch(void* const* d_in, const int* in_sizes, int n_in,
                              void* d_out, int out_size, void* d_ws, size_t ws_size,
                              hipStream_t stream) {
  const float* x       = (const float*)d_in[0];
  const float* pe_s    = (const float*)d_in[1];
  const float* pe_t    = (const float*)d_in[2];
  const float* w_in_s  = (const float*)d_in[3];
  const float* b_in_s  = (const float*)d_in[4];
  const float* alphas  = (const float*)d_in[5];
  const float* att0s   = (const float*)d_in[6];
  const float* w_out_s = (const float*)d_in[7];
  const float* b_out_s = (const float*)d_in[8];
  const float* w_ff_s  = (const float*)d_in[9];
  const float* b_ff_s  = (const float*)d_in[10];
  const float* w_in_t  = (const float*)d_in[11];
  const float* b_in_t  = (const float*)d_in[12];
  const float* alphat  = (const float*)d_in[13];
  const float* att0t   = (const float*)d_in[14];
  const float* w_out_t = (const float*)d_in[15];
  const float* b_out_t = (const float*)d_in[16];
  const float* w_ff_t  = (const float*)d_in[17];
  const float* b_ff_t  = (const float*)d_in[18];
  const float* g_out_s  = (const float*)d_in[19];
  const float* be_out_s = (const float*)d_in[20];
  const float* m_out_s  = (const float*)d_in[21];
  const float* v_out_s  = (const float*)d_in[22];
  const float* g_ff_s   = (const float*)d_in[23];
  const float* be_ff_s  = (const float*)d_in[24];
  const float* m_ff_s   = (const float*)d_in[25];
  const float* v_ff_s   = (const float*)d_in[26];
  const float* g_out_t  = (const float*)d_in[27];
  const float* be_out_t = (const float*)d_in[28];
  const float* m_out_t  = (const float*)d_in[29];
  const float* v_out_t  = (const float*)d_in[30];
  const float* g_ff_t   = (const float*)d_in[31];
  const float* be_ff_t  = (const float*)d_in[32];
  const float* m_ff_t   = (const float*)d_in[33];
  const float* v_ff_t   = (const float*)d_in[34];
  (void)in_sizes; (void)n_in; (void)out_size;

  float* ws = (float*)d_ws;
  float* OUT = (float*)d_out;
  const size_t NS = 204800;  // 128*1600 per-n stride

  const bool full = ws_size >= (size_t)134938624;
  float* SCR;  // full: 19,660,800 fl (qk / half MID); chunk: 4,915,200 fl
  float* ATT;
  float* YB;
  unsigned short* WF;
  if (full) {
    SCR = ws; ATT = ws + 19660800; YB = ws + 20447232;
    WF = (unsigned short*)(ws + 33554432);
  } else {
    SCR = ws; ATT = ws + 4915200; YB = ws + 5701632;
    WF = (unsigned short*)(ws + 18808832);
  }

  // --- weight split (frag offsets in shorts) ---
  SplitArgs sa;
  sa.src[0] = w_in_s;  sa.dst[0] = WF + 0;       sa.K[0] = 128; sa.nfrag[0] = 48;
  sa.src[1] = w_out_s; sa.dst[1] = WF + 49152;   sa.K[1] = 384; sa.nfrag[1] = 96;
  sa.src[2] = w_ff_s;  sa.dst[2] = WF + 147456;  sa.K[2] = 128; sa.nfrag[2] = 32;
  sa.src[3] = w_in_t;  sa.dst[3] = WF + 180224;  sa.K[3] = 128; sa.nfrag[3] = 48;
  sa.src[4] = w_out_t; sa.dst[4] = WF + 229376;  sa.K[4] = 384; sa.nfrag[4] = 96;
  sa.src[5] = w_ff_t;  sa.dst[5] = WF + 327680;  sa.K[5] = 128; sa.nfrag[5] = 32;
  k_split_w<<<dim3(96, 6), 64, 0, stream>>>(sa);

  dim3 blk(256);
  const float* nul = (const float*)0;

  if (full) {
    // ---- spatial ----
    k_mfma_conv<128, 192, 0><<<dim3(25, 64), blk, 0, stream>>>(
        x, pe_s, WF + 0, b_in_s, nul, nul, nul, nul, nul, SCR);
    k_gram_s<<<dim3(3, 64), blk, 0, stream>>>(SCR, alphas, att0s, ATT);
    for (int h = 0; h < 2; ++h) {
      k_apply_s<<<dim3(64, 32), blk, 0, stream>>>(
          x + (size_t)h * 32 * NS, ATT + (size_t)h * 32 * 1875, SCR);
      k_mfma_conv<384, 128, 1><<<dim3(25, 32), blk, 0, stream>>>(
          SCR, nul, WF + 49152, b_out_s, g_out_s, be_out_s, m_out_s, v_out_s,
          x + (size_t)h * 32 * NS, OUT + (size_t)h * 32 * NS);
    }
    k_mfma_conv<128, 128, 1><<<dim3(25, 64), blk, 0, stream>>>(
        OUT, nul, WF + 147456, b_ff_s, g_ff_s, be_ff_s, m_ff_s, v_ff_s, x, YB);
    // ---- temporal ----
    k_mfma_conv<128, 192, 0><<<dim3(25, 64), blk, 0, stream>>>(
        YB, pe_t, WF + 180224, b_in_t, nul, nul, nul, nul, nul, SCR);
    k_gram_t<<<dim3(3, 64), blk, 0, stream>>>(SCR, alphat, att0t, ATT);
    for (int h = 0; h < 2; ++h) {
      k_apply_t<<<dim3(64, 32), blk, 0, stream>>>(
          YB + (size_t)h * 32 * NS, ATT + (size_t)h * 32 * 12288, SCR);
      k_mfma_conv<384, 128, 1><<<dim3(25, 32), blk, 0, stream>>>(
          SCR, nul, WF + 229376, b_out_t, g_out_t, be_out_t, m_out_t, v_out_t,
          YB + (size_t)h * 32 * NS, OUT + (size_t)h * 32 * NS);
    }
    k_mfma_conv<128, 128, 1><<<dim3(25, 64), blk, 0, stream>>>(
        OUT, nul, WF + 327680, b_ff_t, g_ff_t, be_ff_t, m_ff_t, v_ff_t, YB, OUT);
  } else {
    // ---- spatial: qk per quarter (16n), apply/conv per eighth (8n) ----
    for (int h = 0; h < 4; ++h) {
      k_mfma_conv<128, 192, 0><<<dim3(25, 16), blk, 0, stream>>>(
          x + (size_t)h * 16 * NS, pe_s, WF + 0, b_in_s, nul, nul, nul, nul, nul, SCR);
      k_gram_s<<<dim3(3, 16), blk, 0, stream>>>(SCR, alphas, att0s,
                                                ATT + (size_t)h * 16 * 1875);
    }
    for (int e = 0; e < 8; ++e) {
      k_apply_s<<<dim3(64, 8), blk, 0, stream>>>(
          x + (size_t)e * 8 * NS, ATT + (size_t)e * 8 * 1875, SCR);
      k_mfma_conv<384, 128, 1><<<dim3(25, 8), blk, 0, stream>>>(
          SCR, nul, WF + 49152, b_out_s, g_out_s, be_out_s, m_out_s, v_out_s,
          x + (size_t)e * 8 * NS, OUT + (size_t)e * 8 * NS);
    }
    k_mfma_conv<128, 128, 1><<<dim3(25, 64), blk, 0, stream>>>(
        OUT, nul, WF + 147456, b_ff_s, g_ff_s, be_ff_s, m_ff_s, v_ff_s, x, YB);
    // ---- temporal ----
    for (int h = 0; h < 4; ++h) {
      k_mfma_conv<128, 192, 0><<<dim3(25, 16), blk, 0, stream>>>(
          YB + (size_t)h * 16 * NS, pe_t, WF + 180224, b_in_t, nul, nul, nul, nul, nul, SCR);
      k_gram_t<<<dim3(3, 16), blk, 0, stream>>>(SCR, alphat, att0t,
                                                ATT + (size_t)h * 16 * 12288);
    }
    for (int e = 0; e < 8; ++e) {
      k_apply_t<<<dim3(64, 8), blk, 0, stream>>>(
          YB + (size_t)e * 8 * NS, ATT + (size_t)e * 8 * 12288, SCR);
      k_mfma_conv<384, 128, 1><<<dim3(25, 8), blk, 0, stream>>>(
          SCR, nul, WF + 229376, b_out_t, g_out_t, be_out_t, m_out_t, v_out_t,
          YB + (size_t)e * 8 * NS, OUT + (size_t)e * 8 * NS);
    }
    k_mfma_conv<128, 128, 1><<<dim3(25, 64), blk, 0, stream>>>(
        OUT, nul, WF + 327680, b_ff_t, g_ff_t, be_ff_t, m_ff_t, v_ff_t, YB, OUT);
  }
}

// Round 5
// 1036.199 us; speedup vs baseline: 2.7594x; 1.0488x over previous
//
#include <hip/hip_runtime.h>
#include <math.h>

// DSTA-Net block. N=64 C=128 CI=32 S=3 T=64 V=25.
// All GEMM-shaped work (convs AND grams) on bf16 MFMA with hi/lo split
// (fp32-accurate: hh + lh + hl products), attention apply kernels on fp32 VALU.
//
// ws layouts (selected at runtime on ws_size):
//  FULL  (needs 134,938,624 B): QK 19660800 fl | ATT 786432 fl | YB 13107200 fl | WF 720896 B
//  CHUNK (needs  75,956,224 B): SCR 4915200 fl | ATT 786432 fl | YB 13107200 fl | WF 720896 B
// Round-4 FETCH evidence: full path ran (ws_size >= 134.9MB).
// d_out doubles as scratch for YA/ZA stage outputs.

#define EPS_ 1e-5f

typedef short bf16x8 __attribute__((ext_vector_type(8)));
typedef float f32x4 __attribute__((ext_vector_type(4)));

__device__ __forceinline__ unsigned short f2bf(float f) {
  unsigned u = __float_as_uint(f);
  unsigned r = u + 0x7fffu + ((u >> 16) & 1u);
  return (unsigned short)(r >> 16);
}
__device__ __forceinline__ float bf2f(unsigned short h) {
  return __uint_as_float((unsigned)h << 16);
}

// ---------------------------------------------------------------------------
// Weight splitter: W[O][K] fp32 -> fragment-ordered bf16 hi/lo.
// Frag f = ot*(K/32)+ks: hi at f*1024 + lane*8, lo at +512 (shorts).
// Element j of lane l: W[ot*16 + (l&15)][ks*32 + (l>>4)*8 + j].
struct SplitArgs {
  const float* src[6];
  unsigned short* dst[6];
  int K[6];
  int nfrag[6];
};
__global__ __launch_bounds__(64) void k_split_w(SplitArgs a) {
  const int mat = blockIdx.y;
  const int f = blockIdx.x;
  if (f >= a.nfrag[mat]) return;
  const int K = a.K[mat];
  const int ksteps = K >> 5;
  const int ot = f / ksteps, ks = f % ksteps;
  const int l = threadIdx.x;
  const float* sp = a.src[mat] + (size_t)(ot * 16 + (l & 15)) * K + ks * 32 + (l >> 4) * 8;
  float4 f0 = *(const float4*)sp;
  float4 f1 = *(const float4*)(sp + 4);
  float vals[8] = {f0.x, f0.y, f0.z, f0.w, f1.x, f1.y, f1.z, f1.w};
  unsigned short hi[8], lo[8];
#pragma unroll
  for (int j = 0; j < 8; ++j) {
    hi[j] = f2bf(vals[j]);
    lo[j] = f2bf(vals[j] - bf2f(hi[j]));
  }
  unsigned short* d = a.dst[mat] + (size_t)f * 1024 + l * 8;
  uint4 ph, pl;
  ph.x = hi[0] | ((unsigned)hi[1] << 16); ph.y = hi[2] | ((unsigned)hi[3] << 16);
  ph.z = hi[4] | ((unsigned)hi[5] << 16); ph.w = hi[6] | ((unsigned)hi[7] << 16);
  pl.x = lo[0] | ((unsigned)lo[1] << 16); pl.y = lo[2] | ((unsigned)lo[3] << 16);
  pl.z = lo[4] | ((unsigned)lo[5] << 16); pl.w = lo[6] | ((unsigned)lo[7] << 16);
  *(uint4*)d = ph;
  *(uint4*)(d + 512) = pl;
}

// ---------------------------------------------------------------------------
// MFMA conv: out[o,p] = epi( sum_k W[o,k] * Yin[k,p] ), p-tile of 64 per block.
// D[p][o] = A(Y^T) x B(W^T). A staged in LDS [p][k] (pad 136 shorts), hi/lo.
// EPI 0: +bias (qk output). EPI 1: bn(+bias)+residual+leakyrelu.
// grid (25, nN), block 256 (4 waves; wave w owns p-subtile w).
template <int KTOT, int OTOT, int EPI>
__global__ __launch_bounds__(256) void k_mfma_conv(
    const float* __restrict__ Yin, const float* __restrict__ pe,
    const unsigned short* __restrict__ WF, const float* __restrict__ bias,
    const float* __restrict__ g, const float* __restrict__ be,
    const float* __restrict__ bm, const float* __restrict__ bv,
    const float* __restrict__ res, float* __restrict__ out) {
  constexpr int KSTEPS = KTOT / 32;
  constexpr int NCHUNK = KTOT / 128;
  constexpr int OTILES = OTOT / 16;
  const size_t yin_ns = (size_t)KTOT * 1600;
  const size_t out_ns = (size_t)OTOT * 1600;

  __shared__ unsigned short Yhi[64][136];
  __shared__ unsigned short Ylo[64][136];
  __shared__ float ep0[OTOT], ep1[OTOT];

  const int tid = threadIdx.x;
  const int lane = tid & 63, wv = tid >> 6;
  const int n = blockIdx.y, p0 = blockIdx.x * 64;

  for (int i = tid; i < OTOT; i += 256) {
    if (EPI == 1) {
      float inv = g[i] * rsqrtf(bv[i] + EPS_);
      ep0[i] = inv;
      ep1[i] = be[i] + (bias[i] - bm[i]) * inv;
    } else {
      ep0[i] = bias[i];
    }
  }

  f32x4 acc[OTILES];
#pragma unroll
  for (int ot = 0; ot < OTILES; ++ot) acc[ot] = 0;

  const int pl = tid & 63, q = tid >> 6;
  for (int kc = 0; kc < NCHUNK; ++kc) {
    // stage Y^T tile: 128 k x 64 p, transposed into [p][k], hi/lo split
    const float* src = Yin + (size_t)n * yin_ns + (size_t)(kc * 128 + q * 32) * 1600 + p0 + pl;
    const float* pes = pe ? pe + (size_t)(kc * 128 + q * 32) * 1600 + p0 + pl : (const float*)0;
#pragma unroll
    for (int r = 0; r < 8; ++r) {
      float v4[4];
#pragma unroll
      for (int i = 0; i < 4; ++i) {
        v4[i] = src[(size_t)(r * 4 + i) * 1600];
        if (pe) v4[i] += pes[(size_t)(r * 4 + i) * 1600];
      }
      unsigned short h[4], lw[4];
#pragma unroll
      for (int i = 0; i < 4; ++i) {
        h[i] = f2bf(v4[i]);
        lw[i] = f2bf(v4[i] - bf2f(h[i]));
      }
      uint2 ph, plo;
      ph.x = h[0] | ((unsigned)h[1] << 16);  ph.y = h[2] | ((unsigned)h[3] << 16);
      plo.x = lw[0] | ((unsigned)lw[1] << 16); plo.y = lw[2] | ((unsigned)lw[3] << 16);
      *(uint2*)&Yhi[pl][q * 32 + r * 4] = ph;
      *(uint2*)&Ylo[pl][q * 32 + r * 4] = plo;
    }
    __syncthreads();

    const int rowA = wv * 16 + (lane & 15);
    const int kg = (lane >> 4) * 8;
#pragma unroll
    for (int ks = 0; ks < 4; ++ks) {
      bf16x8 ahi = *(const bf16x8*)&Yhi[rowA][ks * 32 + kg];
      bf16x8 alo = *(const bf16x8*)&Ylo[rowA][ks * 32 + kg];
#pragma unroll
      for (int ot = 0; ot < OTILES; ++ot) {
        const unsigned short* wp =
            WF + (size_t)(ot * KSTEPS + kc * 4 + ks) * 1024 + (lane << 3);
        bf16x8 whi = *(const bf16x8*)wp;
        bf16x8 wlo = *(const bf16x8*)(wp + 512);
        acc[ot] = __builtin_amdgcn_mfma_f32_16x16x32_bf16(ahi, whi, acc[ot], 0, 0, 0);
        acc[ot] = __builtin_amdgcn_mfma_f32_16x16x32_bf16(alo, whi, acc[ot], 0, 0, 0);
        acc[ot] = __builtin_amdgcn_mfma_f32_16x16x32_bf16(ahi, wlo, acc[ot], 0, 0, 0);
      }
    }
    __syncthreads();
  }

  // epilogue: lane&15 = o within tile; rows p = p0 + wv*16 + (lane>>4)*4 + j
  const int o_l = lane & 15;
  const int prow = p0 + wv * 16 + ((lane >> 4) << 2);
#pragma unroll
  for (int ot = 0; ot < OTILES; ++ot) {
    const int o = ot * 16 + o_l;
    f32x4 v = acc[ot];
    if (EPI == 1) {
      const float inv = ep0[o], beta = ep1[o];
      const f32x4 rv = *(const f32x4*)(res + (size_t)n * out_ns + (size_t)o * 1600 + prow);
#pragma unroll
      for (int j = 0; j < 4; ++j) {
        float val = v[j] * inv + beta + rv[j];
        v[j] = val > 0.f ? val : 0.1f * val;
      }
    } else {
      const float bo = ep0[o];
#pragma unroll
      for (int j = 0; j < 4; ++j) v[j] += bo;
    }
    *(f32x4*)(out + (size_t)n * out_ns + (size_t)o * 1600 + prow) = v;
  }
}

// ---------------------------------------------------------------------------
// MFMA spatial gram: att_s[n,s,u,v] = tanh(sum_{k=(c,t)} Q[k,u]*K[k,v] /2048)*al + att0.
// M=N=25 (pad 32), K=2048. grid (3, nN), block 256: wave w owns tile (w>>1, w&1).
// Q,K staged per 128-k chunk as bf16 hi/lo in LDS (transposed [u][k]). LDS 34.8KB.
// Pad rows u,v=25..31 hold garbage -> only affect discarded D rows/cols (k not padded).
__global__ __launch_bounds__(256) void k_gram_s(
    const float* __restrict__ qk, const float* __restrict__ alphas,
    const float* __restrict__ att0, float* __restrict__ att) {
  const int s = blockIdx.x, n = blockIdx.y;
  const float* qb = qk + (size_t)(n * 6 + s) * 51200;
  const float* kb = qk + (size_t)(n * 6 + 3 + s) * 51200;
  __shared__ unsigned short Qhi[32][136], Qlo[32][136];
  __shared__ unsigned short Khi[32][136], Klo[32][136];
  const int tid = threadIdx.x;
  const int lane = tid & 63, wv = tid >> 6;
  const int mt = wv >> 1, nt = wv & 1;
  const int rowA = mt * 16 + (lane & 15);
  const int rowB = nt * 16 + (lane & 15);
  const int kg = (lane >> 4) * 8;
  f32x4 acc = 0;
  for (int kc = 0; kc < 16; ++kc) {  // k-chunk = 2 channels x 64 t = 128
    for (int idx = tid; idx < 3200; idx += 256) {
      const int cp = idx / 1600, rem = idx - cp * 1600;
      const int t = rem / 25, u = rem - t * 25;
      const int kl = cp * 64 + t;
      float qv = qb[kc * 3200 + idx];
      float kv = kb[kc * 3200 + idx];
      unsigned short qh = f2bf(qv), kh = f2bf(kv);
      Qhi[u][kl] = qh; Qlo[u][kl] = f2bf(qv - bf2f(qh));
      Khi[u][kl] = kh; Klo[u][kl] = f2bf(kv - bf2f(kh));
    }
    __syncthreads();
#pragma unroll
    for (int ks = 0; ks < 4; ++ks) {
      bf16x8 qh = *(const bf16x8*)&Qhi[rowA][ks * 32 + kg];
      bf16x8 ql = *(const bf16x8*)&Qlo[rowA][ks * 32 + kg];
      bf16x8 kh = *(const bf16x8*)&Khi[rowB][ks * 32 + kg];
      bf16x8 kl = *(const bf16x8*)&Klo[rowB][ks * 32 + kg];
      acc = __builtin_amdgcn_mfma_f32_16x16x32_bf16(qh, kh, acc, 0, 0, 0);
      acc = __builtin_amdgcn_mfma_f32_16x16x32_bf16(ql, kh, acc, 0, 0, 0);
      acc = __builtin_amdgcn_mfma_f32_16x16x32_bf16(qh, kl, acc, 0, 0, 0);
    }
    __syncthreads();
  }
  const float al = alphas[s];
  float* ab = att + (size_t)(n * 3 + s) * 625;
  const int v = nt * 16 + (lane & 15);
  const int u0 = mt * 16 + ((lane >> 4) << 2);
  if (v < 25) {
#pragma unroll
    for (int j = 0; j < 4; ++j) {
      const int u = u0 + j;
      if (u < 25)
        ab[u * 25 + v] = tanhf(acc[j] * (1.0f / 2048.0f)) * al + att0[s * 625 + u * 25 + v];
    }
  }
}

// ---------------------------------------------------------------------------
// MFMA temporal gram: att_t[n,s,t,q] = tanh(sum_{k=(c,v)} Q[k,t]*K[k,q] /800)*al + att0.
// M=N=64, K padded 800->1024 (v'=25..31 zeroed: k-pad MUST be zero). grid (3, nN),
// block 256: wave w owns D rows 16w..16w+15, 4 n-tiles. LDS 69.6KB.
__global__ __launch_bounds__(256) void k_gram_t(
    const float* __restrict__ qk, const float* __restrict__ alphat,
    const float* __restrict__ att0, float* __restrict__ att) {
  const int s = blockIdx.x, n = blockIdx.y;
  const float* qb = qk + (size_t)(n * 6 + s) * 51200;
  const float* kb = qk + (size_t)(n * 6 + 3 + s) * 51200;
  __shared__ unsigned short Qhi[64][136], Qlo[64][136];
  __shared__ unsigned short Khi[64][136], Klo[64][136];
  const int tid = threadIdx.x;
  const int lane = tid & 63, wv = tid >> 6;
  const int rowA = wv * 16 + (lane & 15);
  const int kg = (lane >> 4) * 8;
  // zero the v-pad columns (c'*32 + 25..31) once; staging never writes them
  for (int idx = tid; idx < 64 * 28; idx += 256) {
    const int t = idx / 28, r = idx - t * 28;
    const int col = (r / 7) * 32 + 25 + (r % 7);
    Qhi[t][col] = 0; Qlo[t][col] = 0; Khi[t][col] = 0; Klo[t][col] = 0;
  }
  f32x4 acc[4];
#pragma unroll
  for (int nt = 0; nt < 4; ++nt) acc[nt] = 0;
  for (int cc = 0; cc < 8; ++cc) {  // chunk = 4 channels -> 128 padded k
    for (int idx = tid; idx < 6400; idx += 256) {
      const int cp = idx / 1600, rem = idx - cp * 1600;
      const int t = rem / 25, v = rem - t * 25;
      const int kl = cp * 32 + v;
      float qv = qb[cc * 6400 + idx];
      float kv = kb[cc * 6400 + idx];
      unsigned short qh = f2bf(qv), kh = f2bf(kv);
      Qhi[t][kl] = qh; Qlo[t][kl] = f2bf(qv - bf2f(qh));
      Khi[t][kl] = kh; Klo[t][kl] = f2bf(kv - bf2f(kh));
    }
    __syncthreads();
#pragma unroll
    for (int ks = 0; ks < 4; ++ks) {
      bf16x8 qh = *(const bf16x8*)&Qhi[rowA][ks * 32 + kg];
      bf16x8 ql = *(const bf16x8*)&Qlo[rowA][ks * 32 + kg];
#pragma unroll
      for (int nt = 0; nt < 4; ++nt) {
        const int rowB = nt * 16 + (lane & 15);
        bf16x8 kh = *(const bf16x8*)&Khi[rowB][ks * 32 + kg];
        bf16x8 kl = *(const bf16x8*)&Klo[rowB][ks * 32 + kg];
        acc[nt] = __builtin_amdgcn_mfma_f32_16x16x32_bf16(qh, kh, acc[nt], 0, 0, 0);
        acc[nt] = __builtin_amdgcn_mfma_f32_16x16x32_bf16(ql, kh, acc[nt], 0, 0, 0);
        acc[nt] = __builtin_amdgcn_mfma_f32_16x16x32_bf16(qh, kl, acc[nt], 0, 0, 0);
      }
    }
    __syncthreads();
  }
  const float al = alphat[s];
  float* ab = att + (size_t)(n * 3 + s) * 4096;
  const int t0 = wv * 16 + ((lane >> 4) << 2);
  const int qcol = lane & 15;
#pragma unroll
  for (int nt = 0; nt < 4; ++nt) {
#pragma unroll
    for (int j = 0; j < 4; ++j) {
      const int t = t0 + j, q = nt * 16 + qcol;
      ab[t * 64 + q] =
          tanhf(acc[nt][j] * (1.0f / 800.0f)) * al + att0[(size_t)s * 4096 + t * 64 + q];
    }
  }
}

// ---------------------------------------------------------------------------
// Spatial apply: ya[n,s*128+c, t*25+v] = sum_u x[n,c,t*25+u] * att[n,s,u,v]
// grid (64, nN), block 256. LDS 20.3KB.
__global__ __launch_bounds__(256) void k_apply_s(
    const float* __restrict__ x, const float* __restrict__ att,
    float* __restrict__ ya) {
  const int t = blockIdx.x, n = blockIdx.y;
  __shared__ float xs[128][25];
  __shared__ float al[1875];
  const float* xb = x + (size_t)n * 204800 + t * 25;
  for (int idx = threadIdx.x; idx < 3200; idx += 256)
    xs[idx / 25][idx % 25] = xb[(size_t)(idx / 25) * 1600 + idx % 25];
  for (int idx = threadIdx.x; idx < 1875; idx += 256)
    al[idx] = att[(size_t)n * 1875 + idx];
  __syncthreads();
  float* yb = ya + (size_t)n * 614400 + t * 25;
  for (int idx = threadIdx.x; idx < 9600; idx += 256) {
    const int s = idx / 3200, rem = idx - s * 3200;
    const int c = rem / 25, v = rem % 25;
    const float* ap = al + s * 625 + v;
    float a = 0.f;
#pragma unroll
    for (int u = 0; u < 25; ++u) a += xs[c][u] * ap[u * 25];
    yb[(size_t)(s * 128 + c) * 1600 + v] = a;
  }
}

// ---------------------------------------------------------------------------
// Temporal apply: mid[n, s*128+c, q*25+v] = sum_t y[n,c,t*25+v] * att[n,s,t*64+q]
// grid (64, nN), block 256. LDS 12.8KB.
__global__ __launch_bounds__(256) void k_apply_t(
    const float* __restrict__ y, const float* __restrict__ att,
    float* __restrict__ mid) {
  const int cg = blockIdx.x, n2 = blockIdx.y;
  __shared__ float ys[3200];
  const float* ybase = y + ((size_t)n2 * 128 + cg * 2) * 1600;
  for (int idx = threadIdx.x; idx < 3200; idx += 256) ys[idx] = ybase[idx];
  __syncthreads();
  const float* ab = att + (size_t)n2 * 3 * 4096;
  for (int item = threadIdx.x; item < 1200; item += 256) {
    const int s = item / 400, rem = item % 400, qg = rem / 25, v = rem % 25;
    const int q0 = qg * 4;
    const float* ap = ab + s * 4096 + q0;
    float acc[2][4] = {};
#pragma unroll 4
    for (int t = 0; t < 64; ++t) {
      float4 av = *(const float4*)(ap + t * 64);
      float y0 = ys[t * 25 + v];
      float y1 = ys[1600 + t * 25 + v];
      acc[0][0] += y0 * av.x; acc[0][1] += y0 * av.y; acc[0][2] += y0 * av.z; acc[0][3] += y0 * av.w;
      acc[1][0] += y1 * av.x; acc[1][1] += y1 * av.y; acc[1][2] += y1 * av.z; acc[1][3] += y1 * av.w;
    }
    float* mb = mid + (((size_t)n2 * 3 + s) * 128 + cg * 2) * 1600 + v;
#pragma unroll
    for (int ci = 0; ci < 2; ++ci)
#pragma unroll
      for (int qj = 0; qj < 4; ++qj)
        mb[(size_t)ci * 1600 + (q0 + qj) * 25] = acc[ci][qj];
  }
}

// ---------------------------------------------------------------------------
extern "C" void kernel_launch(void* const* d_in, const int* in_sizes, int n_in,
                              void* d_out, int out_size, void* d_ws, size_t ws_size,
                              hipStream_t stream) {
  const float* x       = (const float*)d_in[0];
  const float* pe_s    = (const float*)d_in[1];
  const float* pe_t    = (const float*)d_in[2];
  const float* w_in_s  = (const float*)d_in[3];
  const float* b_in_s  = (const float*)d_in[4];
  const float* alphas  = (const float*)d_in[5];
  const float* att0s   = (const float*)d_in[6];
  const float* w_out_s = (const float*)d_in[7];
  const float* b_out_s = (const float*)d_in[8];
  const float* w_ff_s  = (const float*)d_in[9];
  const float* b_ff_s  = (const float*)d_in[10];
  const float* w_in_t  = (const float*)d_in[11];
  const float* b_in_t  = (const float*)d_in[12];
  const float* alphat  = (const float*)d_in[13];
  const float* att0t   = (const float*)d_in[14];
  const float* w_out_t = (const float*)d_in[15];
  const float* b_out_t = (const float*)d_in[16];
  const float* w_ff_t  = (const float*)d_in[17];
  const float* b_ff_t  = (const float*)d_in[18];
  const float* g_out_s  = (const float*)d_in[19];
  const float* be_out_s = (const float*)d_in[20];
  const float* m_out_s  = (const float*)d_in[21];
  const float* v_out_s  = (const float*)d_in[22];
  const float* g_ff_s   = (const float*)d_in[23];
  const float* be_ff_s  = (const float*)d_in[24];
  const float* m_ff_s   = (const float*)d_in[25];
  const float* v_ff_s   = (const float*)d_in[26];
  const float* g_out_t  = (const float*)d_in[27];
  const float* be_out_t = (const float*)d_in[28];
  const float* m_out_t  = (const float*)d_in[29];
  const float* v_out_t  = (const float*)d_in[30];
  const float* g_ff_t   = (const float*)d_in[31];
  const float* be_ff_t  = (const float*)d_in[32];
  const float* m_ff_t   = (const float*)d_in[33];
  const float* v_ff_t   = (const float*)d_in[34];
  (void)in_sizes; (void)n_in; (void)out_size;

  float* ws = (float*)d_ws;
  float* OUT = (float*)d_out;
  const size_t NS = 204800;  // 128*1600 per-n stride

  const bool full = ws_size >= (size_t)134938624;
  float* SCR;  // full: 19,660,800 fl (qk / half MID); chunk: 4,915,200 fl
  float* ATT;
  float* YB;
  unsigned short* WF;
  if (full) {
    SCR = ws; ATT = ws + 19660800; YB = ws + 20447232;
    WF = (unsigned short*)(ws + 33554432);
  } else {
    SCR = ws; ATT = ws + 4915200; YB = ws + 5701632;
    WF = (unsigned short*)(ws + 18808832);
  }

  // --- weight split (frag offsets in shorts) ---
  SplitArgs sa;
  sa.src[0] = w_in_s;  sa.dst[0] = WF + 0;       sa.K[0] = 128; sa.nfrag[0] = 48;
  sa.src[1] = w_out_s; sa.dst[1] = WF + 49152;   sa.K[1] = 384; sa.nfrag[1] = 96;
  sa.src[2] = w_ff_s;  sa.dst[2] = WF + 147456;  sa.K[2] = 128; sa.nfrag[2] = 32;
  sa.src[3] = w_in_t;  sa.dst[3] = WF + 180224;  sa.K[3] = 128; sa.nfrag[3] = 48;
  sa.src[4] = w_out_t; sa.dst[4] = WF + 229376;  sa.K[4] = 384; sa.nfrag[4] = 96;
  sa.src[5] = w_ff_t;  sa.dst[5] = WF + 327680;  sa.K[5] = 128; sa.nfrag[5] = 32;
  k_split_w<<<dim3(96, 6), 64, 0, stream>>>(sa);

  dim3 blk(256);
  const float* nul = (const float*)0;

  if (full) {
    // ---- spatial ----
    k_mfma_conv<128, 192, 0><<<dim3(25, 64), blk, 0, stream>>>(
        x, pe_s, WF + 0, b_in_s, nul, nul, nul, nul, nul, SCR);
    k_gram_s<<<dim3(3, 64), blk, 0, stream>>>(SCR, alphas, att0s, ATT);
    for (int h = 0; h < 2; ++h) {
      k_apply_s<<<dim3(64, 32), blk, 0, stream>>>(
          x + (size_t)h * 32 * NS, ATT + (size_t)h * 32 * 1875, SCR);
      k_mfma_conv<384, 128, 1><<<dim3(25, 32), blk, 0, stream>>>(
          SCR, nul, WF + 49152, b_out_s, g_out_s, be_out_s, m_out_s, v_out_s,
          x + (size_t)h * 32 * NS, OUT + (size_t)h * 32 * NS);
    }
    k_mfma_conv<128, 128, 1><<<dim3(25, 64), blk, 0, stream>>>(
        OUT, nul, WF + 147456, b_ff_s, g_ff_s, be_ff_s, m_ff_s, v_ff_s, x, YB);
    // ---- temporal ----
    k_mfma_conv<128, 192, 0><<<dim3(25, 64), blk, 0, stream>>>(
        YB, pe_t, WF + 180224, b_in_t, nul, nul, nul, nul, nul, SCR);
    k_gram_t<<<dim3(3, 64), blk, 0, stream>>>(SCR, alphat, att0t, ATT);
    for (int h = 0; h < 2; ++h) {
      k_apply_t<<<dim3(64, 32), blk, 0, stream>>>(
          YB + (size_t)h * 32 * NS, ATT + (size_t)h * 32 * 12288, SCR);
      k_mfma_conv<384, 128, 1><<<dim3(25, 32), blk, 0, stream>>>(
          SCR, nul, WF + 229376, b_out_t, g_out_t, be_out_t, m_out_t, v_out_t,
          YB + (size_t)h * 32 * NS, OUT + (size_t)h * 32 * NS);
    }
    k_mfma_conv<128, 128, 1><<<dim3(25, 64), blk, 0, stream>>>(
        OUT, nul, WF + 327680, b_ff_t, g_ff_t, be_ff_t, m_ff_t, v_ff_t, YB, OUT);
  } else {
    // ---- spatial: qk per quarter (16n), apply/conv per eighth (8n) ----
    for (int h = 0; h < 4; ++h) {
      k_mfma_conv<128, 192, 0><<<dim3(25, 16), blk, 0, stream>>>(
          x + (size_t)h * 16 * NS, pe_s, WF + 0, b_in_s, nul, nul, nul, nul, nul, SCR);
      k_gram_s<<<dim3(3, 16), blk, 0, stream>>>(SCR, alphas, att0s,
                                                ATT + (size_t)h * 16 * 1875);
    }
    for (int e = 0; e < 8; ++e) {
      k_apply_s<<<dim3(64, 8), blk, 0, stream>>>(
          x + (size_t)e * 8 * NS, ATT + (size_t)e * 8 * 1875, SCR);
      k_mfma_conv<384, 128, 1><<<dim3(25, 8), blk, 0, stream>>>(
          SCR, nul, WF + 49152, b_out_s, g_out_s, be_out_s, m_out_s, v_out_s,
          x + (size_t)e * 8 * NS, OUT + (size_t)e * 8 * NS);
    }
    k_mfma_conv<128, 128, 1><<<dim3(25, 64), blk, 0, stream>>>(
        OUT, nul, WF + 147456, b_ff_s, g_ff_s, be_ff_s, m_ff_s, v_ff_s, x, YB);
    // ---- temporal ----
    for (int h = 0; h < 4; ++h) {
      k_mfma_conv<128, 192, 0><<<dim3(25, 16), blk, 0, stream>>>(
          YB + (size_t)h * 16 * NS, pe_t, WF + 180224, b_in_t, nul, nul, nul, nul, nul, SCR);
      k_gram_t<<<dim3(3, 16), blk, 0, stream>>>(SCR, alphat, att0t,
                                                ATT + (size_t)h * 16 * 12288);
    }
    for (int e = 0; e < 8; ++e) {
      k_apply_t<<<dim3(64, 8), blk, 0, stream>>>(
          YB + (size_t)e * 8 * NS, ATT + (size_t)e * 8 * 12288, SCR);
      k_mfma_conv<384, 128, 1><<<dim3(25, 8), blk, 0, stream>>>(
          SCR, nul, WF + 229376, b_out_t, g_out_t, be_out_t, m_out_t, v_out_t,
          YB + (size_t)e * 8 * NS, OUT + (size_t)e * 8 * NS);
    }
    k_mfma_conv<128, 128, 1><<<dim3(25, 64), blk, 0, stream>>>(
        OUT, nul, WF + 327680, b_ff_t, g_ff_t, be_ff_t, m_ff_t, v_ff_t, YB, OUT);
  }
}

// Round 6
// 895.587 us; speedup vs baseline: 3.1926x; 1.1570x over previous
//
#include <hip/hip_runtime.h>
#include <math.h>

// DSTA-Net block. N=64 C=128 CI=32 S=3 T=64 V=25.
// Convs: barrier-free LDS-free MFMA (A global->reg, B = pre-split WF via L2),
// hi/lo bf16 split (truncated-hi + RNE-lo; err ~2^-16 from dropped ll term).
// Grams: MFMA with LDS-staged hi/lo. Applies: fp32 VALU.
//
// ws layouts (selected at runtime on ws_size):
//  FULL  (needs 134,938,624 B): SCR 19660800 fl | ATT 786432 fl | YB 13107200 fl | WF 720896 B
//  CHUNK (needs  75,956,224 B): SCR 4915200 fl  | ATT 786432 fl | YB 13107200 fl | WF 720896 B
// d_out doubles as scratch for YA/ZA stage outputs.

#define EPS_ 1e-5f

typedef short bf16x8 __attribute__((ext_vector_type(8)));
typedef float f32x4 __attribute__((ext_vector_type(4)));

__device__ __forceinline__ unsigned short f2bf(float f) {
  unsigned u = __float_as_uint(f);
  unsigned r = u + 0x7fffu + ((u >> 16) & 1u);
  return (unsigned short)(r >> 16);
}
__device__ __forceinline__ float bf2f(unsigned short h) {
  return __uint_as_float((unsigned)h << 16);
}

// ---------------------------------------------------------------------------
// Weight splitter: W[O][K] fp32 -> fragment-ordered bf16 hi/lo.
// Frag f = ot*(K/32)+ks: hi at f*1024 + lane*8, lo at +512 (shorts).
// Element j of lane l: W[ot*16 + (l&15)][ks*32 + (l>>4)*8 + j].
struct SplitArgs {
  const float* src[6];
  unsigned short* dst[6];
  int K[6];
  int nfrag[6];
};
__global__ __launch_bounds__(64) void k_split_w(SplitArgs a) {
  const int mat = blockIdx.y;
  const int f = blockIdx.x;
  if (f >= a.nfrag[mat]) return;
  const int K = a.K[mat];
  const int ksteps = K >> 5;
  const int ot = f / ksteps, ks = f % ksteps;
  const int l = threadIdx.x;
  const float* sp = a.src[mat] + (size_t)(ot * 16 + (l & 15)) * K + ks * 32 + (l >> 4) * 8;
  float4 f0 = *(const float4*)sp;
  float4 f1 = *(const float4*)(sp + 4);
  float vals[8] = {f0.x, f0.y, f0.z, f0.w, f1.x, f1.y, f1.z, f1.w};
  unsigned short hi[8], lo[8];
#pragma unroll
  for (int j = 0; j < 8; ++j) {
    hi[j] = f2bf(vals[j]);
    lo[j] = f2bf(vals[j] - bf2f(hi[j]));
  }
  unsigned short* d = a.dst[mat] + (size_t)f * 1024 + l * 8;
  uint4 ph, pl;
  ph.x = hi[0] | ((unsigned)hi[1] << 16); ph.y = hi[2] | ((unsigned)hi[3] << 16);
  ph.z = hi[4] | ((unsigned)hi[5] << 16); ph.w = hi[6] | ((unsigned)hi[7] << 16);
  pl.x = lo[0] | ((unsigned)lo[1] << 16); pl.y = lo[2] | ((unsigned)lo[3] << 16);
  pl.z = lo[4] | ((unsigned)lo[5] << 16); pl.w = lo[6] | ((unsigned)lo[7] << 16);
  *(uint4*)d = ph;
  *(uint4*)(d + 512) = pl;
}

// ---------------------------------------------------------------------------
// Barrier-free reg-MFMA conv: out[o,p] = epi( sum_k W[o,k]*Yin[k,p] ).
// One wave owns PT p-16-tiles x all o. A loaded global->reg per 32-k step
// (1-deep prefetch), B streamed from WF (L2). No LDS, no __syncthreads.
// EPI 0: +bias. EPI 1: bn(+bias)+residual+leakyrelu.
// grid (25, nN), block 256/PT ((4/PT) waves; 64 p per block).
template <int KTOT, int OTOT, int EPI, int PT, bool HASPE>
__global__ __launch_bounds__(256 / PT) void k_conv_reg(
    const float* __restrict__ Yin, const float* __restrict__ pe,
    const unsigned short* __restrict__ WF, const float* __restrict__ bias,
    const float* __restrict__ g, const float* __restrict__ be,
    const float* __restrict__ bm, const float* __restrict__ bv,
    const float* __restrict__ res, float* __restrict__ out) {
  constexpr int KSTEPS = KTOT / 32;
  constexpr int OTILES = OTOT / 16;
  constexpr int WAVES = (256 / PT) / 64;
  const size_t yin_ns = (size_t)KTOT * 1600;
  const size_t out_ns = (size_t)OTOT * 1600;
  const int tid = threadIdx.x, lane = tid & 63, wv = tid >> 6;
  const int n = blockIdx.y;
  const int p0 = (blockIdx.x * WAVES + wv) * (PT * 16);
  const int krow = (lane >> 4) * 8;
  const float* Yb = Yin + (size_t)n * yin_ns;

  f32x4 acc[PT][OTILES];
#pragma unroll
  for (int pp = 0; pp < PT; ++pp)
#pragma unroll
    for (int ot = 0; ot < OTILES; ++ot) acc[pp][ot] = 0;

  float af[PT][8];
#pragma unroll
  for (int j = 0; j < 8; ++j) {
    const size_t ko = (size_t)(krow + j) * 1600;
#pragma unroll
    for (int pp = 0; pp < PT; ++pp) {
      const int pc = p0 + pp * 16 + (lane & 15);
      float v = Yb[ko + pc];
      if (HASPE) v += pe[ko + pc];
      af[pp][j] = v;
    }
  }

  for (int ks = 0; ks < KSTEPS; ++ks) {
    float an[PT][8];
    if (ks + 1 < KSTEPS) {
#pragma unroll
      for (int j = 0; j < 8; ++j) {
        const size_t ko = (size_t)((ks + 1) * 32 + krow + j) * 1600;
#pragma unroll
        for (int pp = 0; pp < PT; ++pp) {
          const int pc = p0 + pp * 16 + (lane & 15);
          float v = Yb[ko + pc];
          if (HASPE) v += pe[ko + pc];
          an[pp][j] = v;
        }
      }
    }
    // convert current A floats -> hi (trunc) / lo (RNE of residual)
    bf16x8 ahi[PT], alo[PT];
#pragma unroll
    for (int pp = 0; pp < PT; ++pp) {
      union { unsigned u[4]; bf16x8 v; } ch, cl;
#pragma unroll
      for (int i = 0; i < 4; ++i) {
        const float fa = af[pp][2 * i], fb = af[pp][2 * i + 1];
        const unsigned ua = __float_as_uint(fa), ub = __float_as_uint(fb);
        ch.u[i] = (ua >> 16) | (ub & 0xffff0000u);
        const float ra = fa - __uint_as_float(ua & 0xffff0000u);
        const float rb = fb - __uint_as_float(ub & 0xffff0000u);
        cl.u[i] = (unsigned)f2bf(ra) | ((unsigned)f2bf(rb) << 16);
      }
      ahi[pp] = ch.v; alo[pp] = cl.v;
    }
#pragma unroll
    for (int ot = 0; ot < OTILES; ++ot) {
      const unsigned short* wp = WF + (size_t)(ot * KSTEPS + ks) * 1024 + (lane << 3);
      bf16x8 whi = *(const bf16x8*)wp;
      bf16x8 wlo = *(const bf16x8*)(wp + 512);
#pragma unroll
      for (int pp = 0; pp < PT; ++pp) {
        acc[pp][ot] = __builtin_amdgcn_mfma_f32_16x16x32_bf16(ahi[pp], whi, acc[pp][ot], 0, 0, 0);
        acc[pp][ot] = __builtin_amdgcn_mfma_f32_16x16x32_bf16(alo[pp], whi, acc[pp][ot], 0, 0, 0);
        acc[pp][ot] = __builtin_amdgcn_mfma_f32_16x16x32_bf16(ahi[pp], wlo, acc[pp][ot], 0, 0, 0);
      }
    }
    if (ks + 1 < KSTEPS) {
#pragma unroll
      for (int pp = 0; pp < PT; ++pp)
#pragma unroll
        for (int j = 0; j < 8; ++j) af[pp][j] = an[pp][j];
    }
  }

  // epilogue: o = ot*16 + (lane&15); rows p = p0 + pp*16 + (lane>>4)*4 + j
  const int o_l = lane & 15;
#pragma unroll
  for (int pp = 0; pp < PT; ++pp) {
    const int prow = p0 + pp * 16 + ((lane >> 4) << 2);
#pragma unroll
    for (int ot = 0; ot < OTILES; ++ot) {
      const int o = ot * 16 + o_l;
      f32x4 v = acc[pp][ot];
      if (EPI == 1) {
        const float inv = g[o] * rsqrtf(bv[o] + EPS_);
        const float beta = be[o] + (bias[o] - bm[o]) * inv;
        const f32x4 rv = *(const f32x4*)(res + (size_t)n * out_ns + (size_t)o * 1600 + prow);
#pragma unroll
        for (int j = 0; j < 4; ++j) {
          float val = v[j] * inv + beta + rv[j];
          v[j] = val > 0.f ? val : 0.1f * val;
        }
      } else {
        const float bo = bias[o];
#pragma unroll
        for (int j = 0; j < 4; ++j) v[j] += bo;
      }
      *(f32x4*)(out + (size_t)n * out_ns + (size_t)o * 1600 + prow) = v;
    }
  }
}

// ---------------------------------------------------------------------------
// MFMA spatial gram: att_s[n,s,u,v] = tanh(sum_{k=(c,t)} Q[k,u]*K[k,v] /2048)*al + att0.
// M=N=25 (pad 32), K=2048. grid (3, nN), block 256: wave w owns tile (w>>1, w&1).
__global__ __launch_bounds__(256) void k_gram_s(
    const float* __restrict__ qk, const float* __restrict__ alphas,
    const float* __restrict__ att0, float* __restrict__ att) {
  const int s = blockIdx.x, n = blockIdx.y;
  const float* qb = qk + (size_t)(n * 6 + s) * 51200;
  const float* kb = qk + (size_t)(n * 6 + 3 + s) * 51200;
  __shared__ unsigned short Qhi[32][136], Qlo[32][136];
  __shared__ unsigned short Khi[32][136], Klo[32][136];
  const int tid = threadIdx.x;
  const int lane = tid & 63, wv = tid >> 6;
  const int mt = wv >> 1, nt = wv & 1;
  const int rowA = mt * 16 + (lane & 15);
  const int rowB = nt * 16 + (lane & 15);
  const int kg = (lane >> 4) * 8;
  f32x4 acc = 0;
  for (int kc = 0; kc < 16; ++kc) {  // k-chunk = 2 channels x 64 t = 128
    for (int idx = tid; idx < 3200; idx += 256) {
      const int cp = idx / 1600, rem = idx - cp * 1600;
      const int t = rem / 25, u = rem - t * 25;
      const int kl = cp * 64 + t;
      float qv = qb[kc * 3200 + idx];
      float kv = kb[kc * 3200 + idx];
      unsigned short qh = f2bf(qv), kh = f2bf(kv);
      Qhi[u][kl] = qh; Qlo[u][kl] = f2bf(qv - bf2f(qh));
      Khi[u][kl] = kh; Klo[u][kl] = f2bf(kv - bf2f(kh));
    }
    __syncthreads();
#pragma unroll
    for (int ks = 0; ks < 4; ++ks) {
      bf16x8 qh = *(const bf16x8*)&Qhi[rowA][ks * 32 + kg];
      bf16x8 ql = *(const bf16x8*)&Qlo[rowA][ks * 32 + kg];
      bf16x8 kh = *(const bf16x8*)&Khi[rowB][ks * 32 + kg];
      bf16x8 kl = *(const bf16x8*)&Klo[rowB][ks * 32 + kg];
      acc = __builtin_amdgcn_mfma_f32_16x16x32_bf16(qh, kh, acc, 0, 0, 0);
      acc = __builtin_amdgcn_mfma_f32_16x16x32_bf16(ql, kh, acc, 0, 0, 0);
      acc = __builtin_amdgcn_mfma_f32_16x16x32_bf16(qh, kl, acc, 0, 0, 0);
    }
    __syncthreads();
  }
  const float al = alphas[s];
  float* ab = att + (size_t)(n * 3 + s) * 625;
  const int v = nt * 16 + (lane & 15);
  const int u0 = mt * 16 + ((lane >> 4) << 2);
  if (v < 25) {
#pragma unroll
    for (int j = 0; j < 4; ++j) {
      const int u = u0 + j;
      if (u < 25)
        ab[u * 25 + v] = tanhf(acc[j] * (1.0f / 2048.0f)) * al + att0[s * 625 + u * 25 + v];
    }
  }
}

// ---------------------------------------------------------------------------
// MFMA temporal gram: att_t[n,s,t,q] = tanh(sum_{k=(c,v)} Q[k,t]*K[k,q] /800)*al + att0.
// M=N=64, K padded 800->1024 (v-pad zeroed). grid (3, nN), block 256.
__global__ __launch_bounds__(256) void k_gram_t(
    const float* __restrict__ qk, const float* __restrict__ alphat,
    const float* __restrict__ att0, float* __restrict__ att) {
  const int s = blockIdx.x, n = blockIdx.y;
  const float* qb = qk + (size_t)(n * 6 + s) * 51200;
  const float* kb = qk + (size_t)(n * 6 + 3 + s) * 51200;
  __shared__ unsigned short Qhi[64][136], Qlo[64][136];
  __shared__ unsigned short Khi[64][136], Klo[64][136];
  const int tid = threadIdx.x;
  const int lane = tid & 63, wv = tid >> 6;
  const int rowA = wv * 16 + (lane & 15);
  const int kg = (lane >> 4) * 8;
  for (int idx = tid; idx < 64 * 28; idx += 256) {
    const int t = idx / 28, r = idx - t * 28;
    const int col = (r / 7) * 32 + 25 + (r % 7);
    Qhi[t][col] = 0; Qlo[t][col] = 0; Khi[t][col] = 0; Klo[t][col] = 0;
  }
  f32x4 acc[4];
#pragma unroll
  for (int nt = 0; nt < 4; ++nt) acc[nt] = 0;
  for (int cc = 0; cc < 8; ++cc) {  // chunk = 4 channels -> 128 padded k
    for (int idx = tid; idx < 6400; idx += 256) {
      const int cp = idx / 1600, rem = idx - cp * 1600;
      const int t = rem / 25, v = rem - t * 25;
      const int kl = cp * 32 + v;
      float qv = qb[cc * 6400 + idx];
      float kv = kb[cc * 6400 + idx];
      unsigned short qh = f2bf(qv), kh = f2bf(kv);
      Qhi[t][kl] = qh; Qlo[t][kl] = f2bf(qv - bf2f(qh));
      Khi[t][kl] = kh; Klo[t][kl] = f2bf(kv - bf2f(kh));
    }
    __syncthreads();
#pragma unroll
    for (int ks = 0; ks < 4; ++ks) {
      bf16x8 qh = *(const bf16x8*)&Qhi[rowA][ks * 32 + kg];
      bf16x8 ql = *(const bf16x8*)&Qlo[rowA][ks * 32 + kg];
#pragma unroll
      for (int nt = 0; nt < 4; ++nt) {
        const int rowB = nt * 16 + (lane & 15);
        bf16x8 kh = *(const bf16x8*)&Khi[rowB][ks * 32 + kg];
        bf16x8 kl = *(const bf16x8*)&Klo[rowB][ks * 32 + kg];
        acc[nt] = __builtin_amdgcn_mfma_f32_16x16x32_bf16(qh, kh, acc[nt], 0, 0, 0);
        acc[nt] = __builtin_amdgcn_mfma_f32_16x16x32_bf16(ql, kh, acc[nt], 0, 0, 0);
        acc[nt] = __builtin_amdgcn_mfma_f32_16x16x32_bf16(qh, kl, acc[nt], 0, 0, 0);
      }
    }
    __syncthreads();
  }
  const float al = alphat[s];
  float* ab = att + (size_t)(n * 3 + s) * 4096;
  const int t0 = wv * 16 + ((lane >> 4) << 2);
  const int qcol = lane & 15;
#pragma unroll
  for (int nt = 0; nt < 4; ++nt) {
#pragma unroll
    for (int j = 0; j < 4; ++j) {
      const int t = t0 + j, q = nt * 16 + qcol;
      ab[t * 64 + q] =
          tanhf(acc[nt][j] * (1.0f / 800.0f)) * al + att0[(size_t)s * 4096 + t * 64 + q];
    }
  }
}

// ---------------------------------------------------------------------------
// Spatial apply: ya[n,s*128+c, t*25+v] = sum_u x[n,c,t*25+u] * att[n,s,u,v]
// grid (64, nN), block 256. LDS 20.3KB.
__global__ __launch_bounds__(256) void k_apply_s(
    const float* __restrict__ x, const float* __restrict__ att,
    float* __restrict__ ya) {
  const int t = blockIdx.x, n = blockIdx.y;
  __shared__ float xs[128][25];
  __shared__ float al[1875];
  const float* xb = x + (size_t)n * 204800 + t * 25;
  for (int idx = threadIdx.x; idx < 3200; idx += 256)
    xs[idx / 25][idx % 25] = xb[(size_t)(idx / 25) * 1600 + idx % 25];
  for (int idx = threadIdx.x; idx < 1875; idx += 256)
    al[idx] = att[(size_t)n * 1875 + idx];
  __syncthreads();
  float* yb = ya + (size_t)n * 614400 + t * 25;
  for (int idx = threadIdx.x; idx < 9600; idx += 256) {
    const int s = idx / 3200, rem = idx - s * 3200;
    const int c = rem / 25, v = rem % 25;
    const float* ap = al + s * 625 + v;
    float a = 0.f;
#pragma unroll
    for (int u = 0; u < 25; ++u) a += xs[c][u] * ap[u * 25];
    yb[(size_t)(s * 128 + c) * 1600 + v] = a;
  }
}

// ---------------------------------------------------------------------------
// Temporal apply: mid[n, s*128+c, q*25+v] = sum_t y[n,c,t*25+v] * att[n,s,t*64+q]
// grid (64, nN), block 256. LDS 12.8KB.
__global__ __launch_bounds__(256) void k_apply_t(
    const float* __restrict__ y, const float* __restrict__ att,
    float* __restrict__ mid) {
  const int cg = blockIdx.x, n2 = blockIdx.y;
  __shared__ float ys[3200];
  const float* ybase = y + ((size_t)n2 * 128 + cg * 2) * 1600;
  for (int idx = threadIdx.x; idx < 3200; idx += 256) ys[idx] = ybase[idx];
  __syncthreads();
  const float* ab = att + (size_t)n2 * 3 * 4096;
  for (int item = threadIdx.x; item < 1200; item += 256) {
    const int s = item / 400, rem = item % 400, qg = rem / 25, v = rem % 25;
    const int q0 = qg * 4;
    const float* ap = ab + s * 4096 + q0;
    float acc[2][4] = {};
#pragma unroll 4
    for (int t = 0; t < 64; ++t) {
      float4 av = *(const float4*)(ap + t * 64);
      float y0 = ys[t * 25 + v];
      float y1 = ys[1600 + t * 25 + v];
      acc[0][0] += y0 * av.x; acc[0][1] += y0 * av.y; acc[0][2] += y0 * av.z; acc[0][3] += y0 * av.w;
      acc[1][0] += y1 * av.x; acc[1][1] += y1 * av.y; acc[1][2] += y1 * av.z; acc[1][3] += y1 * av.w;
    }
    float* mb = mid + (((size_t)n2 * 3 + s) * 128 + cg * 2) * 1600 + v;
#pragma unroll
    for (int ci = 0; ci < 2; ++ci)
#pragma unroll
      for (int qj = 0; qj < 4; ++qj)
        mb[(size_t)ci * 1600 + (q0 + qj) * 25] = acc[ci][qj];
  }
}

// ---------------------------------------------------------------------------
extern "C" void kernel_launch(void* const* d_in, const int* in_sizes, int n_in,
                              void* d_out, int out_size, void* d_ws, size_t ws_size,
                              hipStream_t stream) {
  const float* x       = (const float*)d_in[0];
  const float* pe_s    = (const float*)d_in[1];
  const float* pe_t    = (const float*)d_in[2];
  const float* w_in_s  = (const float*)d_in[3];
  const float* b_in_s  = (const float*)d_in[4];
  const float* alphas  = (const float*)d_in[5];
  const float* att0s   = (const float*)d_in[6];
  const float* w_out_s = (const float*)d_in[7];
  const float* b_out_s = (const float*)d_in[8];
  const float* w_ff_s  = (const float*)d_in[9];
  const float* b_ff_s  = (const float*)d_in[10];
  const float* w_in_t  = (const float*)d_in[11];
  const float* b_in_t  = (const float*)d_in[12];
  const float* alphat  = (const float*)d_in[13];
  const float* att0t   = (const float*)d_in[14];
  const float* w_out_t = (const float*)d_in[15];
  const float* b_out_t = (const float*)d_in[16];
  const float* w_ff_t  = (const float*)d_in[17];
  const float* b_ff_t  = (const float*)d_in[18];
  const float* g_out_s  = (const float*)d_in[19];
  const float* be_out_s = (const float*)d_in[20];
  const float* m_out_s  = (const float*)d_in[21];
  const float* v_out_s  = (const float*)d_in[22];
  const float* g_ff_s   = (const float*)d_in[23];
  const float* be_ff_s  = (const float*)d_in[24];
  const float* m_ff_s   = (const float*)d_in[25];
  const float* v_ff_s   = (const float*)d_in[26];
  const float* g_out_t  = (const float*)d_in[27];
  const float* be_out_t = (const float*)d_in[28];
  const float* m_out_t  = (const float*)d_in[29];
  const float* v_out_t  = (const float*)d_in[30];
  const float* g_ff_t   = (const float*)d_in[31];
  const float* be_ff_t  = (const float*)d_in[32];
  const float* m_ff_t   = (const float*)d_in[33];
  const float* v_ff_t   = (const float*)d_in[34];
  (void)in_sizes; (void)n_in; (void)out_size;

  float* ws = (float*)d_ws;
  float* OUT = (float*)d_out;
  const size_t NS = 204800;  // 128*1600 per-n stride

  const bool full = ws_size >= (size_t)134938624;
  float* SCR;  // full: 19,660,800 fl (qk / half MID); chunk: 4,915,200 fl
  float* ATT;
  float* YB;
  unsigned short* WF;
  if (full) {
    SCR = ws; ATT = ws + 19660800; YB = ws + 20447232;
    WF = (unsigned short*)(ws + 33554432);
  } else {
    SCR = ws; ATT = ws + 4915200; YB = ws + 5701632;
    WF = (unsigned short*)(ws + 18808832);
  }

  // --- weight split (frag offsets in shorts) ---
  SplitArgs sa;
  sa.src[0] = w_in_s;  sa.dst[0] = WF + 0;       sa.K[0] = 128; sa.nfrag[0] = 48;
  sa.src[1] = w_out_s; sa.dst[1] = WF + 49152;   sa.K[1] = 384; sa.nfrag[1] = 96;
  sa.src[2] = w_ff_s;  sa.dst[2] = WF + 147456;  sa.K[2] = 128; sa.nfrag[2] = 32;
  sa.src[3] = w_in_t;  sa.dst[3] = WF + 180224;  sa.K[3] = 128; sa.nfrag[3] = 48;
  sa.src[4] = w_out_t; sa.dst[4] = WF + 229376;  sa.K[4] = 384; sa.nfrag[4] = 96;
  sa.src[5] = w_ff_t;  sa.dst[5] = WF + 327680;  sa.K[5] = 128; sa.nfrag[5] = 32;
  k_split_w<<<dim3(96, 6), 64, 0, stream>>>(sa);

  dim3 blk(256), blk2(128);
  const float* nul = (const float*)0;

  if (full) {
    // ---- spatial ----
    k_conv_reg<128, 192, 0, 1, true><<<dim3(25, 64), blk, 0, stream>>>(
        x, pe_s, WF + 0, b_in_s, nul, nul, nul, nul, nul, SCR);
    k_gram_s<<<dim3(3, 64), blk, 0, stream>>>(SCR, alphas, att0s, ATT);
    for (int h = 0; h < 2; ++h) {
      k_apply_s<<<dim3(64, 32), blk, 0, stream>>>(
          x + (size_t)h * 32 * NS, ATT + (size_t)h * 32 * 1875, SCR);
      k_conv_reg<384, 128, 1, 2, false><<<dim3(25, 32), blk2, 0, stream>>>(
          SCR, nul, WF + 49152, b_out_s, g_out_s, be_out_s, m_out_s, v_out_s,
          x + (size_t)h * 32 * NS, OUT + (size_t)h * 32 * NS);
    }
    k_conv_reg<128, 128, 1, 2, false><<<dim3(25, 64), blk2, 0, stream>>>(
        OUT, nul, WF + 147456, b_ff_s, g_ff_s, be_ff_s, m_ff_s, v_ff_s, x, YB);
    // ---- temporal ----
    k_conv_reg<128, 192, 0, 1, true><<<dim3(25, 64), blk, 0, stream>>>(
        YB, pe_t, WF + 180224, b_in_t, nul, nul, nul, nul, nul, SCR);
    k_gram_t<<<dim3(3, 64), blk, 0, stream>>>(SCR, alphat, att0t, ATT);
    for (int h = 0; h < 2; ++h) {
      k_apply_t<<<dim3(64, 32), blk, 0, stream>>>(
          YB + (size_t)h * 32 * NS, ATT + (size_t)h * 32 * 12288, SCR);
      k_conv_reg<384, 128, 1, 2, false><<<dim3(25, 32), blk2, 0, stream>>>(
          SCR, nul, WF + 229376, b_out_t, g_out_t, be_out_t, m_out_t, v_out_t,
          YB + (size_t)h * 32 * NS, OUT + (size_t)h * 32 * NS);
    }
    k_conv_reg<128, 128, 1, 2, false><<<dim3(25, 64), blk2, 0, stream>>>(
        OUT, nul, WF + 327680, b_ff_t, g_ff_t, be_ff_t, m_ff_t, v_ff_t, YB, OUT);
  } else {
    // ---- spatial: qk per quarter (16n), apply/conv per eighth (8n) ----
    for (int h = 0; h < 4; ++h) {
      k_conv_reg<128, 192, 0, 1, true><<<dim3(25, 16), blk, 0, stream>>>(
          x + (size_t)h * 16 * NS, pe_s, WF + 0, b_in_s, nul, nul, nul, nul, nul, SCR);
      k_gram_s<<<dim3(3, 16), blk, 0, stream>>>(SCR, alphas, att0s,
                                                ATT + (size_t)h * 16 * 1875);
    }
    for (int e = 0; e < 8; ++e) {
      k_apply_s<<<dim3(64, 8), blk, 0, stream>>>(
          x + (size_t)e * 8 * NS, ATT + (size_t)e * 8 * 1875, SCR);
      k_conv_reg<384, 128, 1, 2, false><<<dim3(25, 8), blk2, 0, stream>>>(
          SCR, nul, WF + 49152, b_out_s, g_out_s, be_out_s, m_out_s, v_out_s,
          x + (size_t)e * 8 * NS, OUT + (size_t)e * 8 * NS);
    }
    k_conv_reg<128, 128, 1, 2, false><<<dim3(25, 64), blk2, 0, stream>>>(
        OUT, nul, WF + 147456, b_ff_s, g_ff_s, be_ff_s, m_ff_s, v_ff_s, x, YB);
    // ---- temporal ----
    for (int h = 0; h < 4; ++h) {
      k_conv_reg<128, 192, 0, 1, true><<<dim3(25, 16), blk, 0, stream>>>(
          YB + (size_t)h * 16 * NS, pe_t, WF + 180224, b_in_t, nul, nul, nul, nul, nul, SCR);
      k_gram_t<<<dim3(3, 16), blk, 0, stream>>>(SCR, alphat, att0t,
                                                ATT + (size_t)h * 16 * 12288);
    }
    for (int e = 0; e < 8; ++e) {
      k_apply_t<<<dim3(64, 8), blk, 0, stream>>>(
          YB + (size_t)e * 8 * NS, ATT + (size_t)e * 8 * 12288, SCR);
      k_conv_reg<384, 128, 1, 2, false><<<dim3(25, 8), blk2, 0, stream>>>(
          SCR, nul, WF + 229376, b_out_t, g_out_t, be_out_t, m_out_t, v_out_t,
          YB + (size_t)e * 8 * NS, OUT + (size_t)e * 8 * NS);
    }
    k_conv_reg<128, 128, 1, 2, false><<<dim3(25, 64), blk2, 0, stream>>>(
        OUT, nul, WF + 327680, b_ff_t, g_ff_t, be_ff_t, m_ff_t, v_ff_t, YB, OUT);
  }
}

// Round 7
// 839.864 us; speedup vs baseline: 3.4044x; 1.0663x over previous
//
#include <hip/hip_runtime.h>
#include <math.h>

// DSTA-Net block. N=64 C=128 CI=32 S=3 T=64 V=25.
// Convs: barrier-free LDS-free MFMA (A global->reg, B = pre-split WF via L2),
// hi/lo bf16 split. Grams: MFMA LDS-staged. Applies: fp32 VALU, all-LDS inner loops.
//
// ws layouts (selected at runtime on ws_size):
//  FULL  (needs 134,938,624 B): SCR 19660800 fl | ATT 786432 fl | YB 13107200 fl | WF 720896 B
//  CHUNK (needs  75,956,224 B): SCR 4915200 fl  | ATT 786432 fl | YB 13107200 fl | WF 720896 B
// d_out doubles as scratch for YA/ZA stage outputs.

#define EPS_ 1e-5f

typedef short bf16x8 __attribute__((ext_vector_type(8)));
typedef float f32x4 __attribute__((ext_vector_type(4)));

__device__ __forceinline__ unsigned short f2bf(float f) {
  unsigned u = __float_as_uint(f);
  unsigned r = u + 0x7fffu + ((u >> 16) & 1u);
  return (unsigned short)(r >> 16);
}
__device__ __forceinline__ float bf2f(unsigned short h) {
  return __uint_as_float((unsigned)h << 16);
}

// ---------------------------------------------------------------------------
// Weight splitter: W[O][K] fp32 -> fragment-ordered bf16 hi/lo.
struct SplitArgs {
  const float* src[6];
  unsigned short* dst[6];
  int K[6];
  int nfrag[6];
};
__global__ __launch_bounds__(64) void k_split_w(SplitArgs a) {
  const int mat = blockIdx.y;
  const int f = blockIdx.x;
  if (f >= a.nfrag[mat]) return;
  const int K = a.K[mat];
  const int ksteps = K >> 5;
  const int ot = f / ksteps, ks = f % ksteps;
  const int l = threadIdx.x;
  const float* sp = a.src[mat] + (size_t)(ot * 16 + (l & 15)) * K + ks * 32 + (l >> 4) * 8;
  float4 f0 = *(const float4*)sp;
  float4 f1 = *(const float4*)(sp + 4);
  float vals[8] = {f0.x, f0.y, f0.z, f0.w, f1.x, f1.y, f1.z, f1.w};
  unsigned short hi[8], lo[8];
#pragma unroll
  for (int j = 0; j < 8; ++j) {
    hi[j] = f2bf(vals[j]);
    lo[j] = f2bf(vals[j] - bf2f(hi[j]));
  }
  unsigned short* d = a.dst[mat] + (size_t)f * 1024 + l * 8;
  uint4 ph, pl;
  ph.x = hi[0] | ((unsigned)hi[1] << 16); ph.y = hi[2] | ((unsigned)hi[3] << 16);
  ph.z = hi[4] | ((unsigned)hi[5] << 16); ph.w = hi[6] | ((unsigned)hi[7] << 16);
  pl.x = lo[0] | ((unsigned)lo[1] << 16); pl.y = lo[2] | ((unsigned)lo[3] << 16);
  pl.z = lo[4] | ((unsigned)lo[5] << 16); pl.w = lo[6] | ((unsigned)lo[7] << 16);
  *(uint4*)d = ph;
  *(uint4*)(d + 512) = pl;
}

// ---------------------------------------------------------------------------
// Barrier-free reg-MFMA conv (unchanged from round 6).
template <int KTOT, int OTOT, int EPI, int PT, bool HASPE>
__global__ __launch_bounds__(256 / PT) void k_conv_reg(
    const float* __restrict__ Yin, const float* __restrict__ pe,
    const unsigned short* __restrict__ WF, const float* __restrict__ bias,
    const float* __restrict__ g, const float* __restrict__ be,
    const float* __restrict__ bm, const float* __restrict__ bv,
    const float* __restrict__ res, float* __restrict__ out) {
  constexpr int KSTEPS = KTOT / 32;
  constexpr int OTILES = OTOT / 16;
  constexpr int WAVES = (256 / PT) / 64;
  const size_t yin_ns = (size_t)KTOT * 1600;
  const size_t out_ns = (size_t)OTOT * 1600;
  const int tid = threadIdx.x, lane = tid & 63, wv = tid >> 6;
  const int n = blockIdx.y;
  const int p0 = (blockIdx.x * WAVES + wv) * (PT * 16);
  const int krow = (lane >> 4) * 8;
  const float* Yb = Yin + (size_t)n * yin_ns;

  f32x4 acc[PT][OTILES];
#pragma unroll
  for (int pp = 0; pp < PT; ++pp)
#pragma unroll
    for (int ot = 0; ot < OTILES; ++ot) acc[pp][ot] = 0;

  float af[PT][8];
#pragma unroll
  for (int j = 0; j < 8; ++j) {
    const size_t ko = (size_t)(krow + j) * 1600;
#pragma unroll
    for (int pp = 0; pp < PT; ++pp) {
      const int pc = p0 + pp * 16 + (lane & 15);
      float v = Yb[ko + pc];
      if (HASPE) v += pe[ko + pc];
      af[pp][j] = v;
    }
  }

  for (int ks = 0; ks < KSTEPS; ++ks) {
    float an[PT][8];
    if (ks + 1 < KSTEPS) {
#pragma unroll
      for (int j = 0; j < 8; ++j) {
        const size_t ko = (size_t)((ks + 1) * 32 + krow + j) * 1600;
#pragma unroll
        for (int pp = 0; pp < PT; ++pp) {
          const int pc = p0 + pp * 16 + (lane & 15);
          float v = Yb[ko + pc];
          if (HASPE) v += pe[ko + pc];
          an[pp][j] = v;
        }
      }
    }
    bf16x8 ahi[PT], alo[PT];
#pragma unroll
    for (int pp = 0; pp < PT; ++pp) {
      union { unsigned u[4]; bf16x8 v; } ch, cl;
#pragma unroll
      for (int i = 0; i < 4; ++i) {
        const float fa = af[pp][2 * i], fb = af[pp][2 * i + 1];
        const unsigned ua = __float_as_uint(fa), ub = __float_as_uint(fb);
        ch.u[i] = (ua >> 16) | (ub & 0xffff0000u);
        const float ra = fa - __uint_as_float(ua & 0xffff0000u);
        const float rb = fb - __uint_as_float(ub & 0xffff0000u);
        cl.u[i] = (unsigned)f2bf(ra) | ((unsigned)f2bf(rb) << 16);
      }
      ahi[pp] = ch.v; alo[pp] = cl.v;
    }
#pragma unroll
    for (int ot = 0; ot < OTILES; ++ot) {
      const unsigned short* wp = WF + (size_t)(ot * KSTEPS + ks) * 1024 + (lane << 3);
      bf16x8 whi = *(const bf16x8*)wp;
      bf16x8 wlo = *(const bf16x8*)(wp + 512);
#pragma unroll
      for (int pp = 0; pp < PT; ++pp) {
        acc[pp][ot] = __builtin_amdgcn_mfma_f32_16x16x32_bf16(ahi[pp], whi, acc[pp][ot], 0, 0, 0);
        acc[pp][ot] = __builtin_amdgcn_mfma_f32_16x16x32_bf16(alo[pp], whi, acc[pp][ot], 0, 0, 0);
        acc[pp][ot] = __builtin_amdgcn_mfma_f32_16x16x32_bf16(ahi[pp], wlo, acc[pp][ot], 0, 0, 0);
      }
    }
    if (ks + 1 < KSTEPS) {
#pragma unroll
      for (int pp = 0; pp < PT; ++pp)
#pragma unroll
        for (int j = 0; j < 8; ++j) af[pp][j] = an[pp][j];
    }
  }

  const int o_l = lane & 15;
#pragma unroll
  for (int pp = 0; pp < PT; ++pp) {
    const int prow = p0 + pp * 16 + ((lane >> 4) << 2);
#pragma unroll
    for (int ot = 0; ot < OTILES; ++ot) {
      const int o = ot * 16 + o_l;
      f32x4 v = acc[pp][ot];
      if (EPI == 1) {
        const float inv = g[o] * rsqrtf(bv[o] + EPS_);
        const float beta = be[o] + (bias[o] - bm[o]) * inv;
        const f32x4 rv = *(const f32x4*)(res + (size_t)n * out_ns + (size_t)o * 1600 + prow);
#pragma unroll
        for (int j = 0; j < 4; ++j) {
          float val = v[j] * inv + beta + rv[j];
          v[j] = val > 0.f ? val : 0.1f * val;
        }
      } else {
        const float bo = bias[o];
#pragma unroll
        for (int j = 0; j < 4; ++j) v[j] += bo;
      }
      *(f32x4*)(out + (size_t)n * out_ns + (size_t)o * 1600 + prow) = v;
    }
  }
}

// ---------------------------------------------------------------------------
// MFMA spatial gram (unchanged).
__global__ __launch_bounds__(256) void k_gram_s(
    const float* __restrict__ qk, const float* __restrict__ alphas,
    const float* __restrict__ att0, float* __restrict__ att) {
  const int s = blockIdx.x, n = blockIdx.y;
  const float* qb = qk + (size_t)(n * 6 + s) * 51200;
  const float* kb = qk + (size_t)(n * 6 + 3 + s) * 51200;
  __shared__ unsigned short Qhi[32][136], Qlo[32][136];
  __shared__ unsigned short Khi[32][136], Klo[32][136];
  const int tid = threadIdx.x;
  const int lane = tid & 63, wv = tid >> 6;
  const int mt = wv >> 1, nt = wv & 1;
  const int rowA = mt * 16 + (lane & 15);
  const int rowB = nt * 16 + (lane & 15);
  const int kg = (lane >> 4) * 8;
  f32x4 acc = 0;
  for (int kc = 0; kc < 16; ++kc) {
    for (int idx = tid; idx < 3200; idx += 256) {
      const int cp = idx / 1600, rem = idx - cp * 1600;
      const int t = rem / 25, u = rem - t * 25;
      const int kl = cp * 64 + t;
      float qv = qb[kc * 3200 + idx];
      float kv = kb[kc * 3200 + idx];
      unsigned short qh = f2bf(qv), kh = f2bf(kv);
      Qhi[u][kl] = qh; Qlo[u][kl] = f2bf(qv - bf2f(qh));
      Khi[u][kl] = kh; Klo[u][kl] = f2bf(kv - bf2f(kh));
    }
    __syncthreads();
#pragma unroll
    for (int ks = 0; ks < 4; ++ks) {
      bf16x8 qh = *(const bf16x8*)&Qhi[rowA][ks * 32 + kg];
      bf16x8 ql = *(const bf16x8*)&Qlo[rowA][ks * 32 + kg];
      bf16x8 kh = *(const bf16x8*)&Khi[rowB][ks * 32 + kg];
      bf16x8 kl = *(const bf16x8*)&Klo[rowB][ks * 32 + kg];
      acc = __builtin_amdgcn_mfma_f32_16x16x32_bf16(qh, kh, acc, 0, 0, 0);
      acc = __builtin_amdgcn_mfma_f32_16x16x32_bf16(ql, kh, acc, 0, 0, 0);
      acc = __builtin_amdgcn_mfma_f32_16x16x32_bf16(qh, kl, acc, 0, 0, 0);
    }
    __syncthreads();
  }
  const float al = alphas[s];
  float* ab = att + (size_t)(n * 3 + s) * 625;
  const int v = nt * 16 + (lane & 15);
  const int u0 = mt * 16 + ((lane >> 4) << 2);
  if (v < 25) {
#pragma unroll
    for (int j = 0; j < 4; ++j) {
      const int u = u0 + j;
      if (u < 25)
        ab[u * 25 + v] = tanhf(acc[j] * (1.0f / 2048.0f)) * al + att0[s * 625 + u * 25 + v];
    }
  }
}

// ---------------------------------------------------------------------------
// MFMA temporal gram (unchanged).
__global__ __launch_bounds__(256) void k_gram_t(
    const float* __restrict__ qk, const float* __restrict__ alphat,
    const float* __restrict__ att0, float* __restrict__ att) {
  const int s = blockIdx.x, n = blockIdx.y;
  const float* qb = qk + (size_t)(n * 6 + s) * 51200;
  const float* kb = qk + (size_t)(n * 6 + 3 + s) * 51200;
  __shared__ unsigned short Qhi[64][136], Qlo[64][136];
  __shared__ unsigned short Khi[64][136], Klo[64][136];
  const int tid = threadIdx.x;
  const int lane = tid & 63, wv = tid >> 6;
  const int rowA = wv * 16 + (lane & 15);
  const int kg = (lane >> 4) * 8;
  for (int idx = tid; idx < 64 * 28; idx += 256) {
    const int t = idx / 28, r = idx - t * 28;
    const int col = (r / 7) * 32 + 25 + (r % 7);
    Qhi[t][col] = 0; Qlo[t][col] = 0; Khi[t][col] = 0; Klo[t][col] = 0;
  }
  f32x4 acc[4];
#pragma unroll
  for (int nt = 0; nt < 4; ++nt) acc[nt] = 0;
  for (int cc = 0; cc < 8; ++cc) {
    for (int idx = tid; idx < 6400; idx += 256) {
      const int cp = idx / 1600, rem = idx - cp * 1600;
      const int t = rem / 25, v = rem - t * 25;
      const int kl = cp * 32 + v;
      float qv = qb[cc * 6400 + idx];
      float kv = kb[cc * 6400 + idx];
      unsigned short qh = f2bf(qv), kh = f2bf(kv);
      Qhi[t][kl] = qh; Qlo[t][kl] = f2bf(qv - bf2f(qh));
      Khi[t][kl] = kh; Klo[t][kl] = f2bf(kv - bf2f(kh));
    }
    __syncthreads();
#pragma unroll
    for (int ks = 0; ks < 4; ++ks) {
      bf16x8 qh = *(const bf16x8*)&Qhi[rowA][ks * 32 + kg];
      bf16x8 ql = *(const bf16x8*)&Qlo[rowA][ks * 32 + kg];
#pragma unroll
      for (int nt = 0; nt < 4; ++nt) {
        const int rowB = nt * 16 + (lane & 15);
        bf16x8 kh = *(const bf16x8*)&Khi[rowB][ks * 32 + kg];
        bf16x8 kl = *(const bf16x8*)&Klo[rowB][ks * 32 + kg];
        acc[nt] = __builtin_amdgcn_mfma_f32_16x16x32_bf16(qh, kh, acc[nt], 0, 0, 0);
        acc[nt] = __builtin_amdgcn_mfma_f32_16x16x32_bf16(ql, kh, acc[nt], 0, 0, 0);
        acc[nt] = __builtin_amdgcn_mfma_f32_16x16x32_bf16(qh, kl, acc[nt], 0, 0, 0);
      }
    }
    __syncthreads();
  }
  const float al = alphat[s];
  float* ab = att + (size_t)(n * 3 + s) * 4096;
  const int t0 = wv * 16 + ((lane >> 4) << 2);
  const int qcol = lane & 15;
#pragma unroll
  for (int nt = 0; nt < 4; ++nt) {
#pragma unroll
    for (int j = 0; j < 4; ++j) {
      const int t = t0 + j, q = nt * 16 + qcol;
      ab[t * 64 + q] =
          tanhf(acc[nt][j] * (1.0f / 800.0f)) * al + att0[(size_t)s * 4096 + t * 64 + q];
    }
  }
}

// ---------------------------------------------------------------------------
// Spatial apply v2: ya[n,s*128+c, t*25+v] = sum_u x[n,c,t*25+u] * att[n,s,u,v]
// Thread owns (s,c,v-quad); att LDS padded [3][25][28] -> 1 b128 + 1 b32 per 4 FMA.
// grid (64 t, nN), block 256. LDS 21.2KB.
__global__ __launch_bounds__(256) void k_apply_s(
    const float* __restrict__ x, const float* __restrict__ att,
    float* __restrict__ ya) {
  const int t = blockIdx.x, n = blockIdx.y;
  __shared__ float xs[128][25];
  __shared__ float al[3][25][28];
  const float* xb = x + (size_t)n * 204800 + t * 25;
  for (int idx = threadIdx.x; idx < 3200; idx += 256)
    xs[idx / 25][idx % 25] = xb[(size_t)(idx / 25) * 1600 + idx % 25];
  const float* attb = att + (size_t)n * 1875;
  for (int idx = threadIdx.x; idx < 1875; idx += 256) {
    const int s = idx / 625, rem = idx - s * 625;
    al[s][rem / 25][rem % 25] = attb[idx];
  }
  for (int idx = threadIdx.x; idx < 225; idx += 256) {
    const int s = idx / 75, r = idx - s * 75;
    al[s][r / 3][25 + r % 3] = 0.f;
  }
  __syncthreads();
  float* yb = ya + (size_t)n * 614400 + t * 25;
  for (int item = threadIdx.x; item < 2688; item += 256) {
    const int s = item / 896, r = item - s * 896;
    const int c = r / 7, vq = r - c * 7;
    float a0 = 0.f, a1 = 0.f, a2 = 0.f, a3 = 0.f;
#pragma unroll 5
    for (int u = 0; u < 25; ++u) {
      const float xv = xs[c][u];
      const float4 q4 = *(const float4*)&al[s][u][vq * 4];
      a0 += xv * q4.x; a1 += xv * q4.y; a2 += xv * q4.z; a3 += xv * q4.w;
    }
    float* dst = yb + (size_t)(s * 128 + c) * 1600 + vq * 4;
    const int vrem = 25 - vq * 4;
    dst[0] = a0;
    if (vrem > 1) dst[1] = a1;
    if (vrem > 2) dst[2] = a2;
    if (vrem > 3) dst[3] = a3;
  }
}

// ---------------------------------------------------------------------------
// Temporal apply v2: mid[n, s*128+c, q*25+v] = sum_t y[n,c,t*25+v] * att[n,s,t*64+q]
// att[s] staged in LDS (16KB) -> pure-LDS inner loop (1 b128 + 2 b32 per 8 FMA).
// grid (64 cg, 3 s, nN), block 256. LDS 28.8KB.
__global__ __launch_bounds__(256) void k_apply_t(
    const float* __restrict__ y, const float* __restrict__ att,
    float* __restrict__ mid) {
  const int cg = blockIdx.x, s = blockIdx.y, n2 = blockIdx.z;
  __shared__ float ys[3200];
  __shared__ float at[4096];
  const float* ybase = y + ((size_t)n2 * 128 + cg * 2) * 1600;
  for (int idx = threadIdx.x; idx < 3200; idx += 256) ys[idx] = ybase[idx];
  const float* ab = att + ((size_t)n2 * 3 + s) * 4096;
  for (int idx = threadIdx.x; idx < 4096; idx += 256) at[idx] = ab[idx];
  __syncthreads();
  for (int item = threadIdx.x; item < 400; item += 256) {
    const int qg = item / 25, v = item - qg * 25;
    const int q0 = qg * 4;
    float acc[2][4] = {};
#pragma unroll 4
    for (int t = 0; t < 64; ++t) {
      const float4 av = *(const float4*)&at[t * 64 + q0];
      const float y0 = ys[t * 25 + v];
      const float y1 = ys[1600 + t * 25 + v];
      acc[0][0] += y0 * av.x; acc[0][1] += y0 * av.y; acc[0][2] += y0 * av.z; acc[0][3] += y0 * av.w;
      acc[1][0] += y1 * av.x; acc[1][1] += y1 * av.y; acc[1][2] += y1 * av.z; acc[1][3] += y1 * av.w;
    }
    float* mb = mid + (((size_t)n2 * 3 + s) * 128 + cg * 2) * 1600 + v;
#pragma unroll
    for (int ci = 0; ci < 2; ++ci)
#pragma unroll
      for (int qj = 0; qj < 4; ++qj)
        mb[(size_t)ci * 1600 + (q0 + qj) * 25] = acc[ci][qj];
  }
}

// ---------------------------------------------------------------------------
extern "C" void kernel_launch(void* const* d_in, const int* in_sizes, int n_in,
                              void* d_out, int out_size, void* d_ws, size_t ws_size,
                              hipStream_t stream) {
  const float* x       = (const float*)d_in[0];
  const float* pe_s    = (const float*)d_in[1];
  const float* pe_t    = (const float*)d_in[2];
  const float* w_in_s  = (const float*)d_in[3];
  const float* b_in_s  = (const float*)d_in[4];
  const float* alphas  = (const float*)d_in[5];
  const float* att0s   = (const float*)d_in[6];
  const float* w_out_s = (const float*)d_in[7];
  const float* b_out_s = (const float*)d_in[8];
  const float* w_ff_s  = (const float*)d_in[9];
  const float* b_ff_s  = (const float*)d_in[10];
  const float* w_in_t  = (const float*)d_in[11];
  const float* b_in_t  = (const float*)d_in[12];
  const float* alphat  = (const float*)d_in[13];
  const float* att0t   = (const float*)d_in[14];
  const float* w_out_t = (const float*)d_in[15];
  const float* b_out_t = (const float*)d_in[16];
  const float* w_ff_t  = (const float*)d_in[17];
  const float* b_ff_t  = (const float*)d_in[18];
  const float* g_out_s  = (const float*)d_in[19];
  const float* be_out_s = (const float*)d_in[20];
  const float* m_out_s  = (const float*)d_in[21];
  const float* v_out_s  = (const float*)d_in[22];
  const float* g_ff_s   = (const float*)d_in[23];
  const float* be_ff_s  = (const float*)d_in[24];
  const float* m_ff_s   = (const float*)d_in[25];
  const float* v_ff_s   = (const float*)d_in[26];
  const float* g_out_t  = (const float*)d_in[27];
  const float* be_out_t = (const float*)d_in[28];
  const float* m_out_t  = (const float*)d_in[29];
  const float* v_out_t  = (const float*)d_in[30];
  const float* g_ff_t   = (const float*)d_in[31];
  const float* be_ff_t  = (const float*)d_in[32];
  const float* m_ff_t   = (const float*)d_in[33];
  const float* v_ff_t   = (const float*)d_in[34];
  (void)in_sizes; (void)n_in; (void)out_size;

  float* ws = (float*)d_ws;
  float* OUT = (float*)d_out;
  const size_t NS = 204800;  // 128*1600 per-n stride

  const bool full = ws_size >= (size_t)134938624;
  float* SCR;  // full: 19,660,800 fl (qk / half MID); chunk: 4,915,200 fl
  float* ATT;
  float* YB;
  unsigned short* WF;
  if (full) {
    SCR = ws; ATT = ws + 19660800; YB = ws + 20447232;
    WF = (unsigned short*)(ws + 33554432);
  } else {
    SCR = ws; ATT = ws + 4915200; YB = ws + 5701632;
    WF = (unsigned short*)(ws + 18808832);
  }

  // --- weight split (frag offsets in shorts) ---
  SplitArgs sa;
  sa.src[0] = w_in_s;  sa.dst[0] = WF + 0;       sa.K[0] = 128; sa.nfrag[0] = 48;
  sa.src[1] = w_out_s; sa.dst[1] = WF + 49152;   sa.K[1] = 384; sa.nfrag[1] = 96;
  sa.src[2] = w_ff_s;  sa.dst[2] = WF + 147456;  sa.K[2] = 128; sa.nfrag[2] = 32;
  sa.src[3] = w_in_t;  sa.dst[3] = WF + 180224;  sa.K[3] = 128; sa.nfrag[3] = 48;
  sa.src[4] = w_out_t; sa.dst[4] = WF + 229376;  sa.K[4] = 384; sa.nfrag[4] = 96;
  sa.src[5] = w_ff_t;  sa.dst[5] = WF + 327680;  sa.K[5] = 128; sa.nfrag[5] = 32;
  k_split_w<<<dim3(96, 6), 64, 0, stream>>>(sa);

  dim3 blk(256), blk2(128);
  const float* nul = (const float*)0;

  if (full) {
    // ---- spatial ----
    k_conv_reg<128, 192, 0, 1, true><<<dim3(25, 64), blk, 0, stream>>>(
        x, pe_s, WF + 0, b_in_s, nul, nul, nul, nul, nul, SCR);
    k_gram_s<<<dim3(3, 64), blk, 0, stream>>>(SCR, alphas, att0s, ATT);
    for (int h = 0; h < 2; ++h) {
      k_apply_s<<<dim3(64, 32), blk, 0, stream>>>(
          x + (size_t)h * 32 * NS, ATT + (size_t)h * 32 * 1875, SCR);
      k_conv_reg<384, 128, 1, 1, false><<<dim3(25, 32), blk, 0, stream>>>(
          SCR, nul, WF + 49152, b_out_s, g_out_s, be_out_s, m_out_s, v_out_s,
          x + (size_t)h * 32 * NS, OUT + (size_t)h * 32 * NS);
    }
    k_conv_reg<128, 128, 1, 2, false><<<dim3(25, 64), blk2, 0, stream>>>(
        OUT, nul, WF + 147456, b_ff_s, g_ff_s, be_ff_s, m_ff_s, v_ff_s, x, YB);
    // ---- temporal ----
    k_conv_reg<128, 192, 0, 1, true><<<dim3(25, 64), blk, 0, stream>>>(
        YB, pe_t, WF + 180224, b_in_t, nul, nul, nul, nul, nul, SCR);
    k_gram_t<<<dim3(3, 64), blk, 0, stream>>>(SCR, alphat, att0t, ATT);
    for (int h = 0; h < 2; ++h) {
      k_apply_t<<<dim3(64, 3, 32), blk, 0, stream>>>(
          YB + (size_t)h * 32 * NS, ATT + (size_t)h * 32 * 12288, SCR);
      k_conv_reg<384, 128, 1, 1, false><<<dim3(25, 32), blk, 0, stream>>>(
          SCR, nul, WF + 229376, b_out_t, g_out_t, be_out_t, m_out_t, v_out_t,
          YB + (size_t)h * 32 * NS, OUT + (size_t)h * 32 * NS);
    }
    k_conv_reg<128, 128, 1, 2, false><<<dim3(25, 64), blk2, 0, stream>>>(
        OUT, nul, WF + 327680, b_ff_t, g_ff_t, be_ff_t, m_ff_t, v_ff_t, YB, OUT);
  } else {
    // ---- spatial: qk per quarter (16n), apply/conv per eighth (8n) ----
    for (int h = 0; h < 4; ++h) {
      k_conv_reg<128, 192, 0, 1, true><<<dim3(25, 16), blk, 0, stream>>>(
          x + (size_t)h * 16 * NS, pe_s, WF + 0, b_in_s, nul, nul, nul, nul, nul, SCR);
      k_gram_s<<<dim3(3, 16), blk, 0, stream>>>(SCR, alphas, att0s,
                                                ATT + (size_t)h * 16 * 1875);
    }
    for (int e = 0; e < 8; ++e) {
      k_apply_s<<<dim3(64, 8), blk, 0, stream>>>(
          x + (size_t)e * 8 * NS, ATT + (size_t)e * 8 * 1875, SCR);
      k_conv_reg<384, 128, 1, 1, false><<<dim3(25, 8), blk, 0, stream>>>(
          SCR, nul, WF + 49152, b_out_s, g_out_s, be_out_s, m_out_s, v_out_s,
          x + (size_t)e * 8 * NS, OUT + (size_t)e * 8 * NS);
    }
    k_conv_reg<128, 128, 1, 2, false><<<dim3(25, 64), blk2, 0, stream>>>(
        OUT, nul, WF + 147456, b_ff_s, g_ff_s, be_ff_s, m_ff_s, v_ff_s, x, YB);
    // ---- temporal ----
    for (int h = 0; h < 4; ++h) {
      k_conv_reg<128, 192, 0, 1, true><<<dim3(25, 16), blk, 0, stream>>>(
          YB + (size_t)h * 16 * NS, pe_t, WF + 180224, b_in_t, nul, nul, nul, nul, nul, SCR);
      k_gram_t<<<dim3(3, 16), blk, 0, stream>>>(SCR, alphat, att0t,
                                                ATT + (size_t)h * 16 * 12288);
    }
    for (int e = 0; e < 8; ++e) {
      k_apply_t<<<dim3(64, 3, 8), blk, 0, stream>>>(
          YB + (size_t)e * 8 * NS, ATT + (size_t)e * 8 * 12288, SCR);
      k_conv_reg<384, 128, 1, 1, false><<<dim3(25, 8), blk, 0, stream>>>(
          SCR, nul, WF + 229376, b_out_t, g_out_t, be_out_t, m_out_t, v_out_t,
          YB + (size_t)e * 8 * NS, OUT + (size_t)e * 8 * NS);
    }
    k_conv_reg<128, 128, 1, 2, false><<<dim3(25, 64), blk2, 0, stream>>>(
        OUT, nul, WF + 327680, b_ff_t, g_ff_t, be_ff_t, m_ff_t, v_ff_t, YB, OUT);
  }
}